// Round 6
// baseline (1879.140 us; speedup 1.0000x reference)
//
#include <hip/hip_runtime.h>

typedef _Float16 f16;
typedef _Float16 f16x8 __attribute__((ext_vector_type(8)));
typedef _Float16 f16x4 __attribute__((ext_vector_type(4)));
typedef float f32x4 __attribute__((ext_vector_type(4)));

static constexpr int BB = 2, T = 1024, D = 1024, FFD = 4096, V = 32000, NL = 6;
static constexpr int M = BB * T;                       // 2048 rows
static constexpr int ROWS_PER_LAYER = 4*D + 2*FFD + D; // 13312 scale rows per layer
static constexpr size_t QL = 4ull*D*D + 2ull*FFD*D + (size_t)D*FFD; // 16.78M elems/layer
static constexpr int NT = 64, CT = T / NT;             // scan: 64 chunks x 16 steps
static constexpr int RKV = 3*D;                        // fused rkv row stride

// direct global->LDS, 16B per lane. lds base wave-uniform; HW writes lane i at
// lds + i*16 (m104).
__device__ __forceinline__ void gload16(const f16* g, f16* l) {
  __builtin_amdgcn_global_load_lds(
      (const __attribute__((address_space(1))) void*)g,
      (__attribute__((address_space(3))) void*)l, 16, 0, 0);
}
// counted-vmcnt pipeline helpers (T4): raw barrier, no compiler vmcnt(0) drain.
__device__ __forceinline__ void pipe_fence() {
  asm volatile("s_waitcnt vmcnt(0)" ::: "memory");
  __builtin_amdgcn_s_barrier();
  __builtin_amdgcn_sched_barrier(0);   // no motion across (rule #18/#19)
}

// ---------------------------------------------------------------------------
// Single-pass per-row scale + ternary-quantize to f16 (row held in registers).
// qw layout per layer: [qr(D,D) qk qv qo | q1(FFD,D) q2 | qoc(D,FFD)]
// ---------------------------------------------------------------------------
__global__ __launch_bounds__(256) void quant_kernel(
    const float* __restrict__ Wr, const float* __restrict__ Wk,
    const float* __restrict__ Wv, const float* __restrict__ Wo,
    const float* __restrict__ W1, const float* __restrict__ W2,
    const float* __restrict__ Woc, f16* __restrict__ qw, float* __restrict__ scales)
{
  const int r = blockIdx.x, l = blockIdx.y;
  const float* base; int len; size_t dst;
  if (r < 4*D) {
    const int m = r >> 10, row = r & (D-1);
    const float* Wm = (m==0) ? Wr : (m==1) ? Wk : (m==2) ? Wv : Wo;
    base = Wm + (size_t)l*D*D + (size_t)row*D; len = D;
    dst = (size_t)l*QL + (size_t)m*D*D + (size_t)row*D;
  } else if (r < 4*D + 2*FFD) {
    int row = r - 4*D;
    const int m = row >= FFD; if (m) row -= FFD;
    const float* Wm = m ? W2 : W1;
    base = Wm + (size_t)l*FFD*D + (size_t)row*D; len = D;
    dst = (size_t)l*QL + 4ull*D*D + (size_t)m*FFD*D + (size_t)row*D;
  } else {
    const int row = r - (4*D + 2*FFD);
    base = Woc + (size_t)l*D*FFD + (size_t)row*FFD; len = FFD;
    dst = (size_t)l*QL + 4ull*D*D + 2ull*FFD*D + (size_t)row*FFD;
  }
  const int nv = len >> 10;        // float4s per thread: 1 (len=1024) or 4 (4096)
  float4 rv[4];
  float sum = 0.f;
  #pragma unroll 4
  for (int i = 0; i < 4; ++i) {
    if (i < nv) {
      rv[i] = reinterpret_cast<const float4*>(base)[threadIdx.x + i*256];
      sum += fabsf(rv[i].x) + fabsf(rv[i].y) + fabsf(rv[i].z) + fabsf(rv[i].w);
    }
  }
  #pragma unroll
  for (int off = 32; off > 0; off >>= 1) sum += __shfl_down(sum, off);
  __shared__ float red[4]; __shared__ float sbc;
  if ((threadIdx.x & 63) == 0) red[threadIdx.x >> 6] = sum;
  __syncthreads();
  if (threadIdx.x == 0) {
    const float s = fmaxf((red[0]+red[1]+red[2]+red[3]) / (float)len, 1e-5f);
    sbc = s;
    scales[(size_t)l*ROWS_PER_LAYER + r] = s;
  }
  __syncthreads();
  const float hs = 0.5f * sbc;
  #pragma unroll 4
  for (int i = 0; i < 4; ++i) {
    if (i < nv) {
      const float4 v = rv[i];
      f16x4 q;
      q[0] = v.x > hs ? (f16)1.f : (v.x < -hs ? (f16)-1.f : (f16)0.f);
      q[1] = v.y > hs ? (f16)1.f : (v.y < -hs ? (f16)-1.f : (f16)0.f);
      q[2] = v.z > hs ? (f16)1.f : (v.z < -hs ? (f16)-1.f : (f16)0.f);
      q[3] = v.w > hs ? (f16)1.f : (v.w < -hs ? (f16)-1.f : (f16)0.f);
      reinterpret_cast<f16x4*>(qw + dst)[threadIdx.x + i*256] = q;
    }
  }
}

// f32 -> f16 bulk convert (for embed / head B operand)
__global__ __launch_bounds__(256) void cvt16_kernel(
    const float* __restrict__ x, f16* __restrict__ o, int n4)
{
  const int stride = gridDim.x * 256;
  for (int i = blockIdx.x*256 + threadIdx.x; i < n4; i += stride) {
    const float4 v = reinterpret_cast<const float4*>(x)[i];
    f16x4 q; q[0]=(f16)v.x; q[1]=(f16)v.y; q[2]=(f16)v.z; q[3]=(f16)v.w;
    reinterpret_cast<f16x4*>(o)[i] = q;
  }
}

// ---------------------------------------------------------------------------
// h = rmsnorm(embed[idx], ln_in_w), f32 out. One block (256 thr) per row.
// ---------------------------------------------------------------------------
__global__ __launch_bounds__(256) void embed_rms_kernel(
    const int* __restrict__ idx, const float* __restrict__ embed,
    const float* __restrict__ g, float* __restrict__ h)
{
  const int row = blockIdx.x;
  const int tok = idx[row];
  const float4 xv = reinterpret_cast<const float4*>(embed + (size_t)tok*D)[threadIdx.x];
  float ss = xv.x*xv.x + xv.y*xv.y + xv.z*xv.z + xv.w*xv.w;
  #pragma unroll
  for (int off = 32; off > 0; off >>= 1) ss += __shfl_down(ss, off);
  __shared__ float red[4];
  if ((threadIdx.x & 63) == 0) red[threadIdx.x >> 6] = ss;
  __syncthreads();
  const float mean = (red[0]+red[1]+red[2]+red[3]) * (1.f/(float)D);
  const float rn = rsqrtf(mean + 1e-6f);
  const float4 gv = reinterpret_cast<const float4*>(g)[threadIdx.x];
  float4 ov;
  ov.x = xv.x*rn*gv.x; ov.y = xv.y*rn*gv.y; ov.z = xv.z*rn*gv.z; ov.w = xv.w*rn*gv.w;
  reinterpret_cast<float4*>(h + (size_t)row*D)[threadIdx.x] = ov;
}

// ---------------------------------------------------------------------------
// xn = (f16) rmsnorm(x, g). One block (256 thr) per row of 1024.
// ---------------------------------------------------------------------------
__global__ __launch_bounds__(256) void rms_f16_kernel(
    const float* __restrict__ x, const float* __restrict__ g, f16* __restrict__ o)
{
  const int row = blockIdx.x;
  const float4 xv = reinterpret_cast<const float4*>(x + (size_t)row*D)[threadIdx.x];
  float ss = xv.x*xv.x + xv.y*xv.y + xv.z*xv.z + xv.w*xv.w;
  #pragma unroll
  for (int off = 32; off > 0; off >>= 1) ss += __shfl_down(ss, off);
  __shared__ float red[4];
  if ((threadIdx.x & 63) == 0) red[threadIdx.x >> 6] = ss;
  __syncthreads();
  const float mean = (red[0]+red[1]+red[2]+red[3]) * (1.f/(float)D);
  const float rn = rsqrtf(mean + 1e-6f);
  const float4 gv = reinterpret_cast<const float4*>(g)[threadIdx.x];
  f16x4 ov;
  ov[0] = (f16)(xv.x*rn*gv.x); ov[1] = (f16)(xv.y*rn*gv.y);
  ov[2] = (f16)(xv.z*rn*gv.z); ov[3] = (f16)(xv.w*rn*gv.w);
  reinterpret_cast<f16x4*>(o + (size_t)row*D)[threadIdx.x] = ov;
}

// ---------------------------------------------------------------------------
// Time-mix recurrence as a 3-phase chunked prefix sum over T.
// ---------------------------------------------------------------------------
__global__ __launch_bounds__(256) void scan1_kernel(
    const float* __restrict__ k, const float* __restrict__ v, int ld,
    const float* __restrict__ decay, float* __restrict__ part)
{
  const int d = blockIdx.x*256 + threadIdx.x;
  const int c = blockIdx.y, b = blockIdx.z;
  const float dec = 1.f / (1.f + expf(-decay[d]));
  const float ldc = logf(fmaxf(dec, 1e-7f));
  float sum = 0.f;
  const int row0 = b*T + c*CT;
  #pragma unroll 4
  for (int t = 0; t < CT; ++t) {
    const size_t i = (size_t)(row0 + t)*ld + d;
    const float scale = expf((float)(c*CT + t) * ldc);
    sum += (k[i] * v[i]) / fmaxf(scale, 1e-10f);
  }
  part[((size_t)b*NT + c)*D + d] = sum;
}

__global__ __launch_bounds__(256) void scan2_kernel(float* __restrict__ part)
{
  const int d = blockIdx.x*256 + threadIdx.x;
  const int b = blockIdx.y;
  float run = 0.f;
  #pragma unroll 8
  for (int c = 0; c < NT; ++c) {
    const size_t i = ((size_t)b*NT + c)*D + d;
    const float t = part[i];
    part[i] = run;          // exclusive prefix
    run += t;
  }
}

__global__ __launch_bounds__(256) void scan3_kernel(
    const float* __restrict__ r, const float* __restrict__ k,
    const float* __restrict__ v, int ld, const float* __restrict__ decay,
    const float* __restrict__ part, float* __restrict__ rs)
{
  const int d = blockIdx.x*256 + threadIdx.x;
  const int c = blockIdx.y, b = blockIdx.z;
  const float dec = 1.f / (1.f + expf(-decay[d]));
  const float ldc = logf(fmaxf(dec, 1e-7f));
  float cum = part[((size_t)b*NT + c)*D + d];
  const int row0 = b*T + c*CT;
  #pragma unroll 4
  for (int t = 0; t < CT; ++t) {
    const size_t i = (size_t)(row0 + t)*ld + d;
    const float scale = expf((float)(c*CT + t) * ldc);
    cum += (k[i] * v[i]) / fmaxf(scale, 1e-10f);
    rs[(size_t)(row0 + t)*D + d] = r[i] * (cum * scale);
  }
}

// ---------------------------------------------------------------------------
// g = (f16)( silu(a) * b ), elementwise, vec4. (fallback path only)
// ---------------------------------------------------------------------------
__global__ __launch_bounds__(256) void silumul_kernel(
    const f16* __restrict__ a, const f16* __restrict__ b, f16* __restrict__ o, int n4)
{
  const int i = blockIdx.x*256 + threadIdx.x;
  if (i >= n4) return;
  const f16x4 av = reinterpret_cast<const f16x4*>(a)[i];
  const f16x4 bv = reinterpret_cast<const f16x4*>(b)[i];
  f16x4 ov;
  #pragma unroll
  for (int j = 0; j < 4; ++j) {
    const float x = (float)av[j];
    ov[j] = (f16)((x / (1.f + expf(-x))) * (float)bv[j]);
  }
  reinterpret_cast<f16x4*>(o)[i] = ov;
}

// ---------------------------------------------------------------------------
// XCD-chunked bijective block swizzle (m204): contiguous logical ids per XCD.
// ---------------------------------------------------------------------------
__device__ __forceinline__ int xcd_swizzle(int fid, int nwg) {
  const int q = nwg >> 3, r = nwg & 7, x = fid & 7, o = fid >> 3;
  return (x < r ? x*(q+1) : r*(q+1) + (x-r)*q) + o;
}

// ---------------------------------------------------------------------------
// PIPELINED GEMM (2-phase dbuf, counted-vmcnt): out = epi(scl[n]*A@Bq^T).
// BK=32, linear LDS (T2-null at 2ph: conflicts hidden by schedule; proven
// round 5), global_load_lds staging of tile t+1 issued BEFORE compute of
// tile t; single vmcnt(0)+s_barrier per K-step placed AFTER the MFMAs so
// HBM latency hides under compute. EPI: 0 none, 2 +resid, 3 sigmoid iff
// col<D.
// ---------------------------------------------------------------------------
template<int BM, int BN, int NW, int EPI, bool OUTF16, bool SCALE>
__global__ __launch_bounds__(NW*64) void gemm3_kernel(
    const f16* __restrict__ A, const f16* __restrict__ Bq,
    const float* __restrict__ scl, const float* __restrict__ resid,
    void* __restrict__ outp, int N, int K)
{
  constexpr int WN = BN / 64;            // waves along N
  constexpr int WM = NW / WN;            // waves along M
  constexpr int MF = BM / (WM*16);       // 16-row frags per wave
  constexpr int ACALLS = BM / (16*NW);   // gload16 calls per wave (A), 16 rows each
  constexpr int BCALLS = BN / (16*NW);
  __shared__ f16 As[2][BM*32];
  __shared__ f16 Bs[2][BN*32];

  const int tid = threadIdx.x;
  const int wave = tid >> 6, lane = tid & 63;
  const int gx = gridDim.x, nwg = gx * gridDim.y;
  const int wg = xcd_swizzle(blockIdx.x + blockIdx.y*gx, nwg);
  const int m0 = (wg % gx) * BM, n0 = (wg / gx) * BN;
  const int lr = lane & 15, kg = lane >> 4;
  const int wm0 = (wave / WN) * (MF*16), wn0 = (wave % WN) * 64;
  const int grow = lane >> 2;            // staging: lane -> row in 16-row chunk
  const int gcol = (lane & 3) * 8;       // staging: lane -> 8-f16 col block
  const f16* Ab = A  + (size_t)(m0 + grow)*K + gcol;
  const f16* Bb = Bq + (size_t)(n0 + grow)*K + gcol;

  f32x4 acc[MF][4] = {};

  auto stage = [&](int buf, int k0) {
    #pragma unroll
    for (int c = 0; c < ACALLS; ++c) {
      const int rb = (c*NW + wave) * 16;
      gload16(Ab + (size_t)rb*K + k0, &As[buf][rb*32]);
    }
    #pragma unroll
    for (int c = 0; c < BCALLS; ++c) {
      const int rb = (c*NW + wave) * 16;
      gload16(Bb + (size_t)rb*K + k0, &Bs[buf][rb*32]);
    }
  };

  stage(0, 0);
  pipe_fence();

  const int NKT = K / 32;
  for (int t = 0; t < NKT; ++t) {
    const int cur = t & 1;
    if (t + 1 < NKT) stage(cur ^ 1, (t + 1) * 32);   // prefetch under compute
    f16x8 af[MF], bf[4];
    #pragma unroll
    for (int i = 0; i < MF; ++i)
      af[i] = *reinterpret_cast<const f16x8*>(&As[cur][(wm0 + i*16 + lr)*32 + kg*8]);
    #pragma unroll
    for (int j = 0; j < 4; ++j)
      bf[j] = *reinterpret_cast<const f16x8*>(&Bs[cur][(wn0 + j*16 + lr)*32 + kg*8]);
    #pragma unroll
    for (int i = 0; i < MF; ++i)
      #pragma unroll
      for (int j = 0; j < 4; ++j)
        acc[i][j] = __builtin_amdgcn_mfma_f32_16x16x32_f16(af[i], bf[j], acc[i][j], 0, 0, 0);
    pipe_fence();   // next tile's loads done (latency hidden); buffers safe
  }

  // C/D frag layout: col=lane&15, row=(lane>>4)*4+e
  #pragma unroll
  for (int j = 0; j < 4; ++j) {
    const int col = n0 + wn0 + j*16 + lr;
    const float sv = SCALE ? scl[col] : 1.f;
    #pragma unroll
    for (int i = 0; i < MF; ++i) {
      #pragma unroll
      for (int e = 0; e < 4; ++e) {
        const int row = m0 + wm0 + i*16 + kg*4 + e;
        float y = acc[i][j][e] * sv;
        if (EPI == 3 && col < D) y = 1.f / (1.f + expf(-y));
        if (EPI == 2) y += resid[(size_t)row*N + col];
        if (OUTF16) reinterpret_cast<f16*>(outp)[(size_t)row*N + col] = (f16)y;
        else        reinterpret_cast<float*>(outp)[(size_t)row*N + col] = y;
      }
    }
  }
}

// ---------------------------------------------------------------------------
// PIPELINED FUSED FFN GEMM: g = (f16)( silu(s1[n]*A@B1^T) * (s2[n]*A@B2^T) ).
// Same 2-phase dbuf structure; dual B tiles + dual accumulators.
// ---------------------------------------------------------------------------
__global__ __launch_bounds__(256) void gemm_ffn_kernel(
    const f16* __restrict__ A, const f16* __restrict__ B1, const f16* __restrict__ B2,
    const float* __restrict__ s1, const float* __restrict__ s2,
    f16* __restrict__ outg, int N, int K)
{
  constexpr int BM = 128, BN = 128;
  __shared__ f16 As [2][BM*32];
  __shared__ f16 B1s[2][BN*32];
  __shared__ f16 B2s[2][BN*32];
  const int tid = threadIdx.x;
  const int wave = tid >> 6, lane = tid & 63;
  const int gx = gridDim.x, nwg = gx * gridDim.y;
  const int wg = xcd_swizzle(blockIdx.x + blockIdx.y*gx, nwg);
  const int m0 = (wg % gx) * BM, n0 = (wg / gx) * BN;
  const int lr = lane & 15, kg = lane >> 4;
  const int wm0 = (wave >> 1) * 64, wn0 = (wave & 1) * 64;
  const int grow = lane >> 2, gcol = (lane & 3) * 8;
  const f16* Ab  = A  + (size_t)(m0 + grow)*K + gcol;
  const f16* B1b = B1 + (size_t)(n0 + grow)*K + gcol;
  const f16* B2b = B2 + (size_t)(n0 + grow)*K + gcol;

  f32x4 aca[4][4] = {};
  f32x4 acb[4][4] = {};

  auto stage = [&](int buf, int k0) {
    #pragma unroll
    for (int c = 0; c < 2; ++c) {
      const int rb = (c*4 + wave) * 16;
      gload16(Ab  + (size_t)rb*K + k0, &As [buf][rb*32]);
      gload16(B1b + (size_t)rb*K + k0, &B1s[buf][rb*32]);
      gload16(B2b + (size_t)rb*K + k0, &B2s[buf][rb*32]);
    }
  };

  stage(0, 0);
  pipe_fence();

  const int NKT = K / 32;
  for (int t = 0; t < NKT; ++t) {
    const int cur = t & 1;
    if (t + 1 < NKT) stage(cur ^ 1, (t + 1) * 32);
    f16x8 af[4], b1f[4], b2f[4];
    #pragma unroll
    for (int i = 0; i < 4; ++i)
      af[i] = *reinterpret_cast<const f16x8*>(&As[cur][(wm0 + i*16 + lr)*32 + kg*8]);
    #pragma unroll
    for (int j = 0; j < 4; ++j) {
      b1f[j] = *reinterpret_cast<const f16x8*>(&B1s[cur][(wn0 + j*16 + lr)*32 + kg*8]);
      b2f[j] = *reinterpret_cast<const f16x8*>(&B2s[cur][(wn0 + j*16 + lr)*32 + kg*8]);
    }
    #pragma unroll
    for (int i = 0; i < 4; ++i)
      #pragma unroll
      for (int j = 0; j < 4; ++j) {
        aca[i][j] = __builtin_amdgcn_mfma_f32_16x16x32_f16(af[i], b1f[j], aca[i][j], 0, 0, 0);
        acb[i][j] = __builtin_amdgcn_mfma_f32_16x16x32_f16(af[i], b2f[j], acb[i][j], 0, 0, 0);
      }
    pipe_fence();
  }
  #pragma unroll
  for (int j = 0; j < 4; ++j) {
    const int col = n0 + wn0 + j*16 + lr;
    const float sa = s1[col], sb = s2[col];
    #pragma unroll
    for (int i = 0; i < 4; ++i) {
      #pragma unroll
      for (int e = 0; e < 4; ++e) {
        const int row = m0 + wm0 + i*16 + kg*4 + e;
        const float a = aca[i][j][e] * sa;
        const float b = acb[i][j][e] * sb;
        outg[(size_t)row*N + col] = (f16)((a / (1.f + expf(-a))) * b);
      }
    }
  }
}

// ---------------------------------------------------------------------------
// FALLBACK GEMM: inline quantize from f32 weights (used if ws too small).
// ---------------------------------------------------------------------------
__global__ __launch_bounds__(64) void scales_kernel(
    const float* __restrict__ Wr, const float* __restrict__ Wk,
    const float* __restrict__ Wv, const float* __restrict__ Wo,
    const float* __restrict__ W1, const float* __restrict__ W2,
    const float* __restrict__ Woc, float* __restrict__ s)
{
  const int r = blockIdx.x, l = blockIdx.y;
  const float* base; int len;
  if (r < 4*D) {
    const int m = r >> 10, row = r & (D-1);
    const float* Wm = (m==0) ? Wr : (m==1) ? Wk : (m==2) ? Wv : Wo;
    base = Wm + (size_t)l*D*D + (size_t)row*D; len = D;
  } else if (r < 4*D + 2*FFD) {
    int row = r - 4*D;
    const float* Wm = (row < FFD) ? W1 : W2;
    if (row >= FFD) row -= FFD;
    base = Wm + (size_t)l*FFD*D + (size_t)row*D; len = D;
  } else {
    const int row = r - (4*D + 2*FFD);
    base = Woc + (size_t)l*D*FFD + (size_t)row*FFD; len = FFD;
  }
  float sum = 0.f;
  for (int i = threadIdx.x; i < len; i += 64) sum += fabsf(base[i]);
  #pragma unroll
  for (int off = 32; off > 0; off >>= 1) sum += __shfl_down(sum, off);
  if (threadIdx.x == 0)
    s[(size_t)l*ROWS_PER_LAYER + r] = fmaxf(sum / (float)len, 1e-5f);
}

template<int BM, int EPI, bool QUANT, bool OUTF16>
__global__ __launch_bounds__(256) void gemm_bt_kernel(
    const f16* __restrict__ A, const float* __restrict__ Bw,
    const float* __restrict__ scl, const float* __restrict__ resid,
    void* __restrict__ outp, int N, int K)
{
  constexpr int BN = 128, LDT = 40;
  constexpr int MF = (BM == 128) ? 4 : 2;
  __shared__ f16 As[BM*LDT];
  __shared__ f16 Bs[BN*LDT];
  const int tid = threadIdx.x;
  const int m0 = blockIdx.y * BM, n0 = blockIdx.x * BN;
  const int wave = tid >> 6, lane = tid & 63;
  const int lr = lane & 15, kg = lane >> 4;
  const int wm0 = (wave >> 1) * (MF*16), wn0 = (wave & 1) * 64;
  f32x4 acc[MF][4] = {};
  for (int k0 = 0; k0 < K; k0 += 32) {
    #pragma unroll
    for (int c = 0; c < (BM*4)/256; ++c) {
      const int chunk = tid + c*256;
      const int row = chunk >> 2, c8 = (chunk & 3) << 3;
      *reinterpret_cast<f16x8*>(&As[row*LDT + c8]) =
        *reinterpret_cast<const f16x8*>(A + (size_t)(m0+row)*K + k0 + c8);
    }
    #pragma unroll
    for (int c = 0; c < 2; ++c) {
      const int chunk = tid + c*256;
      const int row = chunk >> 2, c8 = (chunk & 3) << 3;
      const float* bp = Bw + (size_t)(n0+row)*K + k0 + c8;
      const float4 f0 = *reinterpret_cast<const float4*>(bp);
      const float4 f1 = *reinterpret_cast<const float4*>(bp + 4);
      const float wv[8] = {f0.x,f0.y,f0.z,f0.w,f1.x,f1.y,f1.z,f1.w};
      f16x8 qv;
      if (QUANT) {
        const float hs = 0.5f * scl[n0+row];
        #pragma unroll
        for (int j = 0; j < 8; ++j)
          qv[j] = wv[j] > hs ? (f16)1.f : (wv[j] < -hs ? (f16)(-1.f) : (f16)0.f);
      } else {
        #pragma unroll
        for (int j = 0; j < 8; ++j) qv[j] = (f16)wv[j];
      }
      *reinterpret_cast<f16x8*>(&Bs[row*LDT + c8]) = qv;
    }
    __syncthreads();
    f16x8 af[MF], bf[4];
    #pragma unroll
    for (int i = 0; i < MF; ++i)
      af[i] = *reinterpret_cast<const f16x8*>(&As[(wm0 + i*16 + lr)*LDT + kg*8]);
    #pragma unroll
    for (int j = 0; j < 4; ++j)
      bf[j] = *reinterpret_cast<const f16x8*>(&Bs[(wn0 + j*16 + lr)*LDT + kg*8]);
    #pragma unroll
    for (int i = 0; i < MF; ++i)
      #pragma unroll
      for (int j = 0; j < 4; ++j)
        acc[i][j] = __builtin_amdgcn_mfma_f32_16x16x32_f16(af[i], bf[j], acc[i][j], 0, 0, 0);
    __syncthreads();
  }
  #pragma unroll
  for (int j = 0; j < 4; ++j) {
    const int col = n0 + wn0 + j*16 + lr;
    const float sv = QUANT ? scl[col] : 1.f;
    #pragma unroll
    for (int i = 0; i < MF; ++i) {
      #pragma unroll
      for (int e = 0; e < 4; ++e) {
        const int row = m0 + wm0 + i*16 + kg*4 + e;
        float y = acc[i][j][e] * sv;
        if (EPI == 1) y = 1.f / (1.f + expf(-y));
        if (EPI == 2) y += resid[(size_t)row*N + col];
        if (OUTF16) reinterpret_cast<f16*>(outp)[(size_t)row*N + col] = (f16)y;
        else        reinterpret_cast<float*>(outp)[(size_t)row*N + col] = y;
      }
    }
  }
}

// ---------------------------------------------------------------------------
extern "C" void kernel_launch(void* const* d_in, const int* in_sizes, int n_in,
                              void* d_out, int out_size, void* d_ws, size_t ws_size,
                              hipStream_t stream)
{
  (void)in_sizes; (void)n_in; (void)out_size;
  const int*   idx      = (const int*)  d_in[0];
  const float* embed    = (const float*)d_in[1];
  const float* ln_in_w  = (const float*)d_in[2];
  const float* ln1_w    = (const float*)d_in[3];
  const float* Wr       = (const float*)d_in[4];
  const float* Wk       = (const float*)d_in[5];
  const float* Wv       = (const float*)d_in[6];
  const float* Wo_t     = (const float*)d_in[7];
  const float* decay    = (const float*)d_in[8];
  const float* lnx_w    = (const float*)d_in[9];
  const float* ln2_w    = (const float*)d_in[10];
  const float* W1       = (const float*)d_in[11];
  const float* W2       = (const float*)d_in[12];
  const float* Wo_c     = (const float*)d_in[13];
  const float* ln_out_w = (const float*)d_in[14];
  float* out = (float*)d_out;

  char* p = (char*)d_ws;
  auto alloc = [&](size_t bytes) { void* q = (void*)p; p += (bytes + 255) & ~(size_t)255; return q; };
  float* h      = (float*)alloc((size_t)M*D*sizeof(float));
  f16*   xn     = (f16*)  alloc((size_t)M*D*sizeof(f16));
  float* rkv    = (float*)alloc((size_t)M*RKV*sizeof(float));   // fused r|k|v
  float* rsb    = (float*)alloc((size_t)M*D*sizeof(float));
  f16*   abf    = (f16*)  alloc((size_t)M*FFD*sizeof(f16));
  f16*   bbf    = (f16*)  alloc((size_t)M*FFD*sizeof(f16));     // fallback only
  float* scales = (float*)alloc((size_t)NL*ROWS_PER_LAYER*sizeof(float));
  float* part   = (float*)alloc((size_t)BB*NT*D*sizeof(float));
  const size_t base_need = (size_t)(p - (char*)d_ws);
  const size_t fast_need = base_need + (NL*QL*sizeof(f16) + 256) + ((size_t)V*D*sizeof(f16) + 256);

  embed_rms_kernel<<<M, 256, 0, stream>>>(idx, embed, ln_in_w, h);

  const dim3 gS(D/256, NT, BB);   // scan1/scan3: 512 blocks
  const dim3 gS2(D/256, BB);      // scan2: 8 blocks

  if (ws_size >= fast_need) {
    // ================= FAST PATH: pre-quantized f16 weights =================
    f16* qw      = (f16*)alloc(NL*QL*sizeof(f16));
    f16* embed16 = (f16*)alloc((size_t)V*D*sizeof(f16));
    quant_kernel<<<dim3(ROWS_PER_LAYER, NL), 256, 0, stream>>>(Wr, Wk, Wv, Wo_t, W1, W2, Wo_c, qw, scales);
    cvt16_kernel<<<2048, 256, 0, stream>>>(embed, embed16, V*D/4);

    const dim3 gRKV(M/128, RKV/128);  // 16 x 24 = 384 blocks
    const dim3 gO(M/64, D/128);       // 32 x 8  = 256 blocks
    const dim3 gFFN(M/128, FFD/128);  // 16 x 32 = 512 blocks
    const dim3 gHEAD(M/128, V/256);   // 16 x 125 = 2000 blocks, 8 waves

    for (int l = 0; l < NL; ++l) {
      const float* sl = scales + (size_t)l*ROWS_PER_LAYER;
      const f16* qb = qw + (size_t)l*QL;
      const f16 *qrkv = qb, *qo = qb + 3ull*D*D;
      const f16 *q1 = qb + 4ull*D*D, *q2 = qb + 4ull*D*D + (size_t)FFD*D;
      const f16 *qoc = qb + 4ull*D*D + 2ull*(size_t)FFD*D;
      const float* dcy = decay + (size_t)l*D;
      // ---- time mix ----
      rms_f16_kernel<<<M, 256, 0, stream>>>(h, ln1_w + (size_t)l*D, xn);
      gemm3_kernel<128,128,4,3,false,true><<<gRKV, 256, 0, stream>>>(xn, qrkv, sl, nullptr, rkv, RKV, D);
      scan1_kernel<<<gS, 256, 0, stream>>>(rkv + D, rkv + 2*D, RKV, dcy, part);
      scan2_kernel<<<gS2, 256, 0, stream>>>(part);
      scan3_kernel<<<gS, 256, 0, stream>>>(rkv, rkv + D, rkv + 2*D, RKV, dcy, part, rsb);
      rms_f16_kernel<<<M, 256, 0, stream>>>(rsb, lnx_w + (size_t)l*D, xn);
      gemm3_kernel<64,128,4,2,false,true><<<gO, 256, 0, stream>>>(xn, qo, sl + 3*D, h, h, D, D);
      // ---- channel mix ----
      rms_f16_kernel<<<M, 256, 0, stream>>>(h, ln2_w + (size_t)l*D, xn);
      gemm_ffn_kernel<<<gFFN, 256, 0, stream>>>(xn, q1, q2, sl + 4*D, sl + 4*D + FFD, abf, FFD, D);
      gemm3_kernel<64,128,4,2,false,true><<<gO, 256, 0, stream>>>(abf, qoc, sl + 4*D + 2*FFD, h, h, D, FFD);
    }
    rms_f16_kernel<<<M, 256, 0, stream>>>(h, ln_out_w, xn);
    gemm3_kernel<128,256,8,0,false,false><<<gHEAD, 512, 0, stream>>>(xn, embed16, nullptr, nullptr, out, V, D);
  } else {
    // ================= FALLBACK: inline-quant path =================
    float* rbuf = rkv;                       // reuse rkv region as 3 buffers
    float* kbuf = rkv + (size_t)M*D;
    float* vbuf = rkv + 2ull*M*D;
    scales_kernel<<<dim3(ROWS_PER_LAYER, NL), 64, 0, stream>>>(Wr, Wk, Wv, Wo_t, W1, W2, Wo_c, scales);
    const dim3 gD(D/128, M/64);
    const dim3 gF(FFD/128, M/128);
    for (int l = 0; l < NL; ++l) {
      const float* sl = scales + (size_t)l*ROWS_PER_LAYER;
      const float* dcy = decay + (size_t)l*D;
      rms_f16_kernel<<<M, 256, 0, stream>>>(h, ln1_w + (size_t)l*D, xn);
      gemm_bt_kernel<64,1,true,false><<<gD, 256, 0, stream>>>(xn, Wr + (size_t)l*D*D, sl,       nullptr, rbuf, D, D);
      gemm_bt_kernel<64,0,true,false><<<gD, 256, 0, stream>>>(xn, Wk + (size_t)l*D*D, sl + D,   nullptr, kbuf, D, D);
      gemm_bt_kernel<64,0,true,false><<<gD, 256, 0, stream>>>(xn, Wv + (size_t)l*D*D, sl + 2*D, nullptr, vbuf, D, D);
      scan1_kernel<<<gS, 256, 0, stream>>>(kbuf, vbuf, D, dcy, part);
      scan2_kernel<<<gS2, 256, 0, stream>>>(part);
      scan3_kernel<<<gS, 256, 0, stream>>>(rbuf, kbuf, vbuf, D, dcy, part, rsb);
      rms_f16_kernel<<<M, 256, 0, stream>>>(rsb, lnx_w + (size_t)l*D, xn);
      gemm_bt_kernel<64,2,true,false><<<gD, 256, 0, stream>>>(xn, Wo_t + (size_t)l*D*D, sl + 3*D, h, h, D, D);
      rms_f16_kernel<<<M, 256, 0, stream>>>(h, ln2_w + (size_t)l*D, xn);
      gemm_bt_kernel<128,0,true,true><<<gF, 256, 0, stream>>>(xn, W1 + (size_t)l*FFD*D, sl + 4*D,       nullptr, abf, FFD, D);
      gemm_bt_kernel<128,0,true,true><<<gF, 256, 0, stream>>>(xn, W2 + (size_t)l*FFD*D, sl + 4*D + FFD, nullptr, bbf, FFD, D);
      silumul_kernel<<<(M*FFD/4)/256, 256, 0, stream>>>(abf, bbf, abf, M*FFD/4);
      gemm_bt_kernel<64,2,true,false><<<gD, 256, 0, stream>>>(abf, Wo_c + (size_t)l*D*FFD, sl + 4*D + 2*FFD, h, h, D, FFD);
    }
    rms_f16_kernel<<<M, 256, 0, stream>>>(h, ln_out_w, xn);
    gemm_bt_kernel<128,0,false,false><<<dim3(V/128, M/128), 256, 0, stream>>>(xn, embed, nullptr, nullptr, out, V, D);
  }
}

// Round 7
// 1572.416 us; speedup vs baseline: 1.1951x; 1.1951x over previous
//
#include <hip/hip_runtime.h>

typedef _Float16 f16;
typedef _Float16 f16x8 __attribute__((ext_vector_type(8)));
typedef _Float16 f16x4 __attribute__((ext_vector_type(4)));
typedef float f32x4 __attribute__((ext_vector_type(4)));

static constexpr int BB = 2, T = 1024, D = 1024, FFD = 4096, V = 32000, NL = 6;
static constexpr int M = BB * T;                       // 2048 rows
static constexpr int ROWS_PER_LAYER = 4*D + 2*FFD + D; // 13312 scale rows per layer
static constexpr size_t QL = 4ull*D*D + 2ull*FFD*D + (size_t)D*FFD; // 16.78M elems/layer
static constexpr int NT = 64, CT = T / NT;             // scan: 64 chunks x 16 steps
static constexpr int RKV = 3*D;                        // fused rkv row stride

// direct global->LDS, 16B per lane. lds base wave-uniform; HW writes lane i at
// lds + i*16 (m104).
__device__ __forceinline__ void gload16(const f16* g, f16* l) {
  __builtin_amdgcn_global_load_lds(
      (const __attribute__((address_space(1))) void*)g,
      (__attribute__((address_space(3))) void*)l, 16, 0, 0);
}

// ---------------------------------------------------------------------------
// Single-pass per-row scale + ternary-quantize to f16 (row held in registers).
// qw layout per layer: [qr(D,D) qk qv qo | q1(FFD,D) q2 | qoc(D,FFD)]
// ---------------------------------------------------------------------------
__global__ __launch_bounds__(256) void quant_kernel(
    const float* __restrict__ Wr, const float* __restrict__ Wk,
    const float* __restrict__ Wv, const float* __restrict__ Wo,
    const float* __restrict__ W1, const float* __restrict__ W2,
    const float* __restrict__ Woc, f16* __restrict__ qw, float* __restrict__ scales)
{
  const int r = blockIdx.x, l = blockIdx.y;
  const float* base; int len; size_t dst;
  if (r < 4*D) {
    const int m = r >> 10, row = r & (D-1);
    const float* Wm = (m==0) ? Wr : (m==1) ? Wk : (m==2) ? Wv : Wo;
    base = Wm + (size_t)l*D*D + (size_t)row*D; len = D;
    dst = (size_t)l*QL + (size_t)m*D*D + (size_t)row*D;
  } else if (r < 4*D + 2*FFD) {
    int row = r - 4*D;
    const int m = row >= FFD; if (m) row -= FFD;
    const float* Wm = m ? W2 : W1;
    base = Wm + (size_t)l*FFD*D + (size_t)row*D; len = D;
    dst = (size_t)l*QL + 4ull*D*D + (size_t)m*FFD*D + (size_t)row*D;
  } else {
    const int row = r - (4*D + 2*FFD);
    base = Woc + (size_t)l*D*FFD + (size_t)row*FFD; len = FFD;
    dst = (size_t)l*QL + 4ull*D*D + 2ull*FFD*D + (size_t)row*FFD;
  }
  const int nv = len >> 10;        // float4s per thread: 1 (len=1024) or 4 (4096)
  float4 rv[4];
  float sum = 0.f;
  #pragma unroll 4
  for (int i = 0; i < 4; ++i) {
    if (i < nv) {
      rv[i] = reinterpret_cast<const float4*>(base)[threadIdx.x + i*256];
      sum += fabsf(rv[i].x) + fabsf(rv[i].y) + fabsf(rv[i].z) + fabsf(rv[i].w);
    }
  }
  #pragma unroll
  for (int off = 32; off > 0; off >>= 1) sum += __shfl_down(sum, off);
  __shared__ float red[4]; __shared__ float sbc;
  if ((threadIdx.x & 63) == 0) red[threadIdx.x >> 6] = sum;
  __syncthreads();
  if (threadIdx.x == 0) {
    const float s = fmaxf((red[0]+red[1]+red[2]+red[3]) / (float)len, 1e-5f);
    sbc = s;
    scales[(size_t)l*ROWS_PER_LAYER + r] = s;
  }
  __syncthreads();
  const float hs = 0.5f * sbc;
  #pragma unroll 4
  for (int i = 0; i < 4; ++i) {
    if (i < nv) {
      const float4 v = rv[i];
      f16x4 q;
      q[0] = v.x > hs ? (f16)1.f : (v.x < -hs ? (f16)-1.f : (f16)0.f);
      q[1] = v.y > hs ? (f16)1.f : (v.y < -hs ? (f16)-1.f : (f16)0.f);
      q[2] = v.z > hs ? (f16)1.f : (v.z < -hs ? (f16)-1.f : (f16)0.f);
      q[3] = v.w > hs ? (f16)1.f : (v.w < -hs ? (f16)-1.f : (f16)0.f);
      reinterpret_cast<f16x4*>(qw + dst)[threadIdx.x + i*256] = q;
    }
  }
}

// f32 -> f16 bulk convert (for embed / head B operand)
__global__ __launch_bounds__(256) void cvt16_kernel(
    const float* __restrict__ x, f16* __restrict__ o, int n4)
{
  const int stride = gridDim.x * 256;
  for (int i = blockIdx.x*256 + threadIdx.x; i < n4; i += stride) {
    const float4 v = reinterpret_cast<const float4*>(x)[i];
    f16x4 q; q[0]=(f16)v.x; q[1]=(f16)v.y; q[2]=(f16)v.z; q[3]=(f16)v.w;
    reinterpret_cast<f16x4*>(o)[i] = q;
  }
}

// ---------------------------------------------------------------------------
// h = rmsnorm(embed[idx], ln_in_w), f32 out. One block (256 thr) per row.
// ---------------------------------------------------------------------------
__global__ __launch_bounds__(256) void embed_rms_kernel(
    const int* __restrict__ idx, const float* __restrict__ embed,
    const float* __restrict__ g, float* __restrict__ h)
{
  const int row = blockIdx.x;
  const int tok = idx[row];
  const float4 xv = reinterpret_cast<const float4*>(embed + (size_t)tok*D)[threadIdx.x];
  float ss = xv.x*xv.x + xv.y*xv.y + xv.z*xv.z + xv.w*xv.w;
  #pragma unroll
  for (int off = 32; off > 0; off >>= 1) ss += __shfl_down(ss, off);
  __shared__ float red[4];
  if ((threadIdx.x & 63) == 0) red[threadIdx.x >> 6] = ss;
  __syncthreads();
  const float mean = (red[0]+red[1]+red[2]+red[3]) * (1.f/(float)D);
  const float rn = rsqrtf(mean + 1e-6f);
  const float4 gv = reinterpret_cast<const float4*>(g)[threadIdx.x];
  float4 ov;
  ov.x = xv.x*rn*gv.x; ov.y = xv.y*rn*gv.y; ov.z = xv.z*rn*gv.z; ov.w = xv.w*rn*gv.w;
  reinterpret_cast<float4*>(h + (size_t)row*D)[threadIdx.x] = ov;
}

// ---------------------------------------------------------------------------
// xn = (f16) rmsnorm(x, g). One block (256 thr) per row of 1024.
// ---------------------------------------------------------------------------
__global__ __launch_bounds__(256) void rms_f16_kernel(
    const float* __restrict__ x, const float* __restrict__ g, f16* __restrict__ o)
{
  const int row = blockIdx.x;
  const float4 xv = reinterpret_cast<const float4*>(x + (size_t)row*D)[threadIdx.x];
  float ss = xv.x*xv.x + xv.y*xv.y + xv.z*xv.z + xv.w*xv.w;
  #pragma unroll
  for (int off = 32; off > 0; off >>= 1) ss += __shfl_down(ss, off);
  __shared__ float red[4];
  if ((threadIdx.x & 63) == 0) red[threadIdx.x >> 6] = ss;
  __syncthreads();
  const float mean = (red[0]+red[1]+red[2]+red[3]) * (1.f/(float)D);
  const float rn = rsqrtf(mean + 1e-6f);
  const float4 gv = reinterpret_cast<const float4*>(g)[threadIdx.x];
  f16x4 ov;
  ov[0] = (f16)(xv.x*rn*gv.x); ov[1] = (f16)(xv.y*rn*gv.y);
  ov[2] = (f16)(xv.z*rn*gv.z); ov[3] = (f16)(xv.w*rn*gv.w);
  reinterpret_cast<f16x4*>(o + (size_t)row*D)[threadIdx.x] = ov;
}

// ---------------------------------------------------------------------------
// Time-mix recurrence as a 3-phase chunked prefix sum over T.
// ---------------------------------------------------------------------------
__global__ __launch_bounds__(256) void scan1_kernel(
    const float* __restrict__ k, const float* __restrict__ v, int ld,
    const float* __restrict__ decay, float* __restrict__ part)
{
  const int d = blockIdx.x*256 + threadIdx.x;
  const int c = blockIdx.y, b = blockIdx.z;
  const float dec = 1.f / (1.f + expf(-decay[d]));
  const float ldc = logf(fmaxf(dec, 1e-7f));
  float sum = 0.f;
  const int row0 = b*T + c*CT;
  #pragma unroll 4
  for (int t = 0; t < CT; ++t) {
    const size_t i = (size_t)(row0 + t)*ld + d;
    const float scale = expf((float)(c*CT + t) * ldc);
    sum += (k[i] * v[i]) / fmaxf(scale, 1e-10f);
  }
  part[((size_t)b*NT + c)*D + d] = sum;
}

__global__ __launch_bounds__(256) void scan2_kernel(float* __restrict__ part)
{
  const int d = blockIdx.x*256 + threadIdx.x;
  const int b = blockIdx.y;
  float run = 0.f;
  #pragma unroll 8
  for (int c = 0; c < NT; ++c) {
    const size_t i = ((size_t)b*NT + c)*D + d;
    const float t = part[i];
    part[i] = run;          // exclusive prefix
    run += t;
  }
}

__global__ __launch_bounds__(256) void scan3_kernel(
    const float* __restrict__ r, const float* __restrict__ k,
    const float* __restrict__ v, int ld, const float* __restrict__ decay,
    const float* __restrict__ part, float* __restrict__ rs)
{
  const int d = blockIdx.x*256 + threadIdx.x;
  const int c = blockIdx.y, b = blockIdx.z;
  const float dec = 1.f / (1.f + expf(-decay[d]));
  const float ldc = logf(fmaxf(dec, 1e-7f));
  float cum = part[((size_t)b*NT + c)*D + d];
  const int row0 = b*T + c*CT;
  #pragma unroll 4
  for (int t = 0; t < CT; ++t) {
    const size_t i = (size_t)(row0 + t)*ld + d;
    const float scale = expf((float)(c*CT + t) * ldc);
    cum += (k[i] * v[i]) / fmaxf(scale, 1e-10f);
    rs[(size_t)(row0 + t)*D + d] = r[i] * (cum * scale);
  }
}

// ---------------------------------------------------------------------------
// g = (f16)( silu(a) * b ), elementwise, vec4. (fallback path only)
// ---------------------------------------------------------------------------
__global__ __launch_bounds__(256) void silumul_kernel(
    const f16* __restrict__ a, const f16* __restrict__ b, f16* __restrict__ o, int n4)
{
  const int i = blockIdx.x*256 + threadIdx.x;
  if (i >= n4) return;
  const f16x4 av = reinterpret_cast<const f16x4*>(a)[i];
  const f16x4 bv = reinterpret_cast<const f16x4*>(b)[i];
  f16x4 ov;
  #pragma unroll
  for (int j = 0; j < 4; ++j) {
    const float x = (float)av[j];
    ov[j] = (f16)((x / (1.f + expf(-x))) * (float)bv[j]);
  }
  reinterpret_cast<f16x4*>(o)[i] = ov;
}

// split-K reduce: h += p0 + p1 (vec4)
__global__ __launch_bounds__(256) void radd_kernel(
    float* __restrict__ h, const float* __restrict__ p0,
    const float* __restrict__ p1, int n4)
{
  const int i = blockIdx.x*256 + threadIdx.x;
  if (i >= n4) return;
  float4 a = reinterpret_cast<float4*>(h)[i];
  const float4 b = reinterpret_cast<const float4*>(p0)[i];
  const float4 c = reinterpret_cast<const float4*>(p1)[i];
  a.x += b.x + c.x; a.y += b.y + c.y; a.z += b.z + c.z; a.w += b.w + c.w;
  reinterpret_cast<float4*>(h)[i] = a;
}

// ---------------------------------------------------------------------------
// XCD-chunked bijective block swizzle (m204): contiguous logical ids per XCD.
// ---------------------------------------------------------------------------
__device__ __forceinline__ int xcd_swizzle(int fid, int nwg) {
  const int q = nwg >> 3, r = nwg & 7, x = fid & 7, o = fid >> 3;
  return (x < r ? x*(q+1) : r*(q+1) + (x-r)*q) + o;
}

// ---------------------------------------------------------------------------
// FAST GEMM (round-4 proven structure + NW + XCD swizzle + optional split-K):
// out[M,N] = epi(scl[n] * A[M,K] @ Bq[N,K]^T). BK=32, LINEAR LDS, two
// __syncthreads per K-step, NO manual fences (compiler schedules best —
// rounds 5/6 proved manual fencing regresses). BN=128; NW in {4,8}.
// EPI: 0 none, 2 +resid, 3 sigmoid iff col<D.
// SPLITK: gridDim.z pieces; piece z covers K/z cols, writes outp+z*M*N.
// ---------------------------------------------------------------------------
template<int BM, int NW, int EPI, bool OUTF16, bool SCALE, bool SPLITK = false>
__global__ __launch_bounds__(NW*64) void gemm_q_kernel(
    const f16* __restrict__ A, const f16* __restrict__ Bq,
    const float* __restrict__ scl, const float* __restrict__ resid,
    void* __restrict__ outp, int N, int K)
{
  constexpr int WN = 2;                  // waves along N (BN=128)
  constexpr int WM = NW / WN;            // waves along M
  constexpr int MF = BM / (WM*16);       // 16-row frags per wave
  constexpr int ACALLS = BM / (16*NW);   // gload16 calls per wave (16 rows each)
  constexpr int BCALLS = 128 / (16*NW);
  __shared__ f16 As[BM*32];
  __shared__ f16 Bs[128*32];

  const int tid = threadIdx.x;
  const int wave = tid >> 6, lane = tid & 63;
  const int gx = gridDim.x, nwg = gx * gridDim.y;
  const int wg = xcd_swizzle(blockIdx.x + blockIdx.y*gx, nwg);
  const int m0 = (wg % gx) * BM, n0 = (wg / gx) * 128;
  const int lr = lane & 15, kg = lane >> 4;
  const int wm0 = (wave / WN) * (MF*16), wn0 = (wave % WN) * 64;
  const int grow = lane >> 2;            // staging: lane -> row in 16-row chunk
  const int gcol = (lane & 3) * 8;       // staging: lane -> 8-f16 col block
  const f16* Ab = A  + (size_t)(m0 + grow)*K + gcol;
  const f16* Bb = Bq + (size_t)(n0 + grow)*K + gcol;

  int kbeg = 0, kend = K;
  size_t obase = 0;
  if (SPLITK) {
    const int kc = K / gridDim.z;
    kbeg = blockIdx.z * kc; kend = kbeg + kc;
    obase = (size_t)blockIdx.z * M * (size_t)N;
  }

  f32x4 acc[MF][4] = {};

  for (int k0 = kbeg; k0 < kend; k0 += 32) {
    #pragma unroll
    for (int c = 0; c < ACALLS; ++c) {
      const int rb = (c*NW + wave) * 16;
      gload16(Ab + (size_t)rb*K + k0, &As[rb*32]);
    }
    #pragma unroll
    for (int c = 0; c < BCALLS; ++c) {
      const int rb = (c*NW + wave) * 16;
      gload16(Bb + (size_t)rb*K + k0, &Bs[rb*32]);
    }
    __syncthreads();
    f16x8 af[MF], bf[4];
    #pragma unroll
    for (int i = 0; i < MF; ++i)
      af[i] = *reinterpret_cast<const f16x8*>(&As[(wm0 + i*16 + lr)*32 + kg*8]);
    #pragma unroll
    for (int j = 0; j < 4; ++j)
      bf[j] = *reinterpret_cast<const f16x8*>(&Bs[(wn0 + j*16 + lr)*32 + kg*8]);
    #pragma unroll
    for (int i = 0; i < MF; ++i)
      #pragma unroll
      for (int j = 0; j < 4; ++j)
        acc[i][j] = __builtin_amdgcn_mfma_f32_16x16x32_f16(af[i], bf[j], acc[i][j], 0, 0, 0);
    __syncthreads();
  }

  // C/D frag layout: col=lane&15, row=(lane>>4)*4+e
  #pragma unroll
  for (int j = 0; j < 4; ++j) {
    const int col = n0 + wn0 + j*16 + lr;
    const float sv = SCALE ? scl[col] : 1.f;
    #pragma unroll
    for (int i = 0; i < MF; ++i) {
      #pragma unroll
      for (int e = 0; e < 4; ++e) {
        const int row = m0 + wm0 + i*16 + kg*4 + e;
        float y = acc[i][j][e] * sv;
        if (EPI == 3 && col < D) y = 1.f / (1.f + expf(-y));
        if (EPI == 2) y += resid[(size_t)row*N + col];
        if (OUTF16) reinterpret_cast<f16*>(outp)[(size_t)row*N + col] = (f16)y;
        else        reinterpret_cast<float*>(outp)[obase + (size_t)row*N + col] = y;
      }
    }
  }
}

// ---------------------------------------------------------------------------
// HEAD GEMM (round-4 proven + XCD swizzle): 128x256 tile, 8 waves, BK=32.
// ---------------------------------------------------------------------------
__global__ __launch_bounds__(512, 2) void gemm_head_kernel(
    const f16* __restrict__ A, const f16* __restrict__ Bq,
    float* __restrict__ out, int N, int K)
{
  constexpr int BM = 128, BN = 256;
  __shared__ f16 As[BM*32];
  __shared__ f16 Bs[BN*32];
  const int tid = threadIdx.x;
  const int wave = tid >> 6, lane = tid & 63;
  const int gx = gridDim.x, nwg = gx * gridDim.y;
  const int wg = xcd_swizzle(blockIdx.x + blockIdx.y*gx, nwg);
  const int m0 = (wg % gx) * BM, n0 = (wg / gx) * BN;
  const int lr = lane & 15, kg = lane >> 4;
  const int wm0 = (wave >> 2) * 64, wn0 = (wave & 3) * 64;
  const int grow = lane >> 2, gcol = (lane & 3) * 8;

  f32x4 acc[4][4] = {};
  const f16* Ab = A  + (size_t)(m0 + grow)*K + gcol;
  const f16* Bb = Bq + (size_t)(n0 + grow)*K + gcol;

  for (int k0 = 0; k0 < K; k0 += 32) {
    gload16(Ab + (size_t)(wave*16)*K + k0, &As[(wave*16)*32]);
    gload16(Bb + (size_t)(wave*16)*K + k0, &Bs[(wave*16)*32]);
    gload16(Bb + (size_t)((wave+8)*16)*K + k0, &Bs[((wave+8)*16)*32]);
    __syncthreads();
    f16x8 af[4], bf[4];
    #pragma unroll
    for (int i = 0; i < 4; ++i)
      af[i] = *reinterpret_cast<const f16x8*>(&As[(wm0 + i*16 + lr)*32 + kg*8]);
    #pragma unroll
    for (int j = 0; j < 4; ++j)
      bf[j] = *reinterpret_cast<const f16x8*>(&Bs[(wn0 + j*16 + lr)*32 + kg*8]);
    #pragma unroll
    for (int i = 0; i < 4; ++i)
      #pragma unroll
      for (int j = 0; j < 4; ++j)
        acc[i][j] = __builtin_amdgcn_mfma_f32_16x16x32_f16(af[i], bf[j], acc[i][j], 0, 0, 0);
    __syncthreads();
  }
  #pragma unroll
  for (int j = 0; j < 4; ++j) {
    const int col = n0 + wn0 + j*16 + lr;
    #pragma unroll
    for (int i = 0; i < 4; ++i) {
      #pragma unroll
      for (int e = 0; e < 4; ++e) {
        const int row = m0 + wm0 + i*16 + kg*4 + e;
        out[(size_t)row*N + col] = acc[i][j][e];
      }
    }
  }
}

// ---------------------------------------------------------------------------
// FUSED FFN GEMM (round-4 structure, NW=8, XCD swizzle):
// g = (f16)( silu(s1[n]*A@B1^T) * (s2[n]*A@B2^T) ). 128x128 tile, 8 waves.
// ---------------------------------------------------------------------------
__global__ __launch_bounds__(512) void gemm_ffn_kernel(
    const f16* __restrict__ A, const f16* __restrict__ B1, const f16* __restrict__ B2,
    const float* __restrict__ s1, const float* __restrict__ s2,
    f16* __restrict__ outg, int N, int K)
{
  constexpr int BM = 128, BN = 128;
  __shared__ f16 As [BM*32];
  __shared__ f16 B1s[BN*32];
  __shared__ f16 B2s[BN*32];
  const int tid = threadIdx.x;
  const int wave = tid >> 6, lane = tid & 63;
  const int gx = gridDim.x, nwg = gx * gridDim.y;
  const int wg = xcd_swizzle(blockIdx.x + blockIdx.y*gx, nwg);
  const int m0 = (wg % gx) * BM, n0 = (wg / gx) * BN;
  const int lr = lane & 15, kg = lane >> 4;
  const int wm0 = (wave >> 1) * 32, wn0 = (wave & 1) * 64;  // 8 waves: 4M x 2N
  const int grow = lane >> 2, gcol = (lane & 3) * 8;
  const f16* Ab  = A  + (size_t)(m0 + grow)*K + gcol;
  const f16* B1b = B1 + (size_t)(n0 + grow)*K + gcol;
  const f16* B2b = B2 + (size_t)(n0 + grow)*K + gcol;

  f32x4 aca[2][4] = {};
  f32x4 acb[2][4] = {};

  for (int k0 = 0; k0 < K; k0 += 32) {
    {
      const int rb = wave * 16;
      gload16(Ab  + (size_t)rb*K + k0, &As [rb*32]);
      gload16(B1b + (size_t)rb*K + k0, &B1s[rb*32]);
      gload16(B2b + (size_t)rb*K + k0, &B2s[rb*32]);
    }
    __syncthreads();
    f16x8 af[2], b1f[4], b2f[4];
    #pragma unroll
    for (int i = 0; i < 2; ++i)
      af[i] = *reinterpret_cast<const f16x8*>(&As[(wm0 + i*16 + lr)*32 + kg*8]);
    #pragma unroll
    for (int j = 0; j < 4; ++j) {
      b1f[j] = *reinterpret_cast<const f16x8*>(&B1s[(wn0 + j*16 + lr)*32 + kg*8]);
      b2f[j] = *reinterpret_cast<const f16x8*>(&B2s[(wn0 + j*16 + lr)*32 + kg*8]);
    }
    #pragma unroll
    for (int i = 0; i < 2; ++i)
      #pragma unroll
      for (int j = 0; j < 4; ++j) {
        aca[i][j] = __builtin_amdgcn_mfma_f32_16x16x32_f16(af[i], b1f[j], aca[i][j], 0, 0, 0);
        acb[i][j] = __builtin_amdgcn_mfma_f32_16x16x32_f16(af[i], b2f[j], acb[i][j], 0, 0, 0);
      }
    __syncthreads();
  }
  #pragma unroll
  for (int j = 0; j < 4; ++j) {
    const int col = n0 + wn0 + j*16 + lr;
    const float sa = s1[col], sb = s2[col];
    #pragma unroll
    for (int i = 0; i < 2; ++i) {
      #pragma unroll
      for (int e = 0; e < 4; ++e) {
        const int row = m0 + wm0 + i*16 + kg*4 + e;
        const float a = aca[i][j][e] * sa;
        const float b = acb[i][j][e] * sb;
        outg[(size_t)row*N + col] = (f16)((a / (1.f + expf(-a))) * b);
      }
    }
  }
}

// ---------------------------------------------------------------------------
// FALLBACK GEMM: inline quantize from f32 weights (used if ws too small).
// ---------------------------------------------------------------------------
__global__ __launch_bounds__(64) void scales_kernel(
    const float* __restrict__ Wr, const float* __restrict__ Wk,
    const float* __restrict__ Wv, const float* __restrict__ Wo,
    const float* __restrict__ W1, const float* __restrict__ W2,
    const float* __restrict__ Woc, float* __restrict__ s)
{
  const int r = blockIdx.x, l = blockIdx.y;
  const float* base; int len;
  if (r < 4*D) {
    const int m = r >> 10, row = r & (D-1);
    const float* Wm = (m==0) ? Wr : (m==1) ? Wk : (m==2) ? Wv : Wo;
    base = Wm + (size_t)l*D*D + (size_t)row*D; len = D;
  } else if (r < 4*D + 2*FFD) {
    int row = r - 4*D;
    const float* Wm = (row < FFD) ? W1 : W2;
    if (row >= FFD) row -= FFD;
    base = Wm + (size_t)l*FFD*D + (size_t)row*D; len = D;
  } else {
    const int row = r - (4*D + 2*FFD);
    base = Woc + (size_t)l*D*FFD + (size_t)row*FFD; len = FFD;
  }
  float sum = 0.f;
  for (int i = threadIdx.x; i < len; i += 64) sum += fabsf(base[i]);
  #pragma unroll
  for (int off = 32; off > 0; off >>= 1) sum += __shfl_down(sum, off);
  if (threadIdx.x == 0)
    s[(size_t)l*ROWS_PER_LAYER + r] = fmaxf(sum / (float)len, 1e-5f);
}

template<int BM, int EPI, bool QUANT, bool OUTF16>
__global__ __launch_bounds__(256) void gemm_bt_kernel(
    const f16* __restrict__ A, const float* __restrict__ Bw,
    const float* __restrict__ scl, const float* __restrict__ resid,
    void* __restrict__ outp, int N, int K)
{
  constexpr int BN = 128, LDT = 40;
  constexpr int MF = (BM == 128) ? 4 : 2;
  __shared__ f16 As[BM*LDT];
  __shared__ f16 Bs[BN*LDT];
  const int tid = threadIdx.x;
  const int m0 = blockIdx.y * BM, n0 = blockIdx.x * BN;
  const int wave = tid >> 6, lane = tid & 63;
  const int lr = lane & 15, kg = lane >> 4;
  const int wm0 = (wave >> 1) * (MF*16), wn0 = (wave & 1) * 64;
  f32x4 acc[MF][4] = {};
  for (int k0 = 0; k0 < K; k0 += 32) {
    #pragma unroll
    for (int c = 0; c < (BM*4)/256; ++c) {
      const int chunk = tid + c*256;
      const int row = chunk >> 2, c8 = (chunk & 3) << 3;
      *reinterpret_cast<f16x8*>(&As[row*LDT + c8]) =
        *reinterpret_cast<const f16x8*>(A + (size_t)(m0+row)*K + k0 + c8);
    }
    #pragma unroll
    for (int c = 0; c < 2; ++c) {
      const int chunk = tid + c*256;
      const int row = chunk >> 2, c8 = (chunk & 3) << 3;
      const float* bp = Bw + (size_t)(n0+row)*K + k0 + c8;
      const float4 f0 = *reinterpret_cast<const float4*>(bp);
      const float4 f1 = *reinterpret_cast<const float4*>(bp + 4);
      const float wv[8] = {f0.x,f0.y,f0.z,f0.w,f1.x,f1.y,f1.z,f1.w};
      f16x8 qv;
      if (QUANT) {
        const float hs = 0.5f * scl[n0+row];
        #pragma unroll
        for (int j = 0; j < 8; ++j)
          qv[j] = wv[j] > hs ? (f16)1.f : (wv[j] < -hs ? (f16)(-1.f) : (f16)0.f);
      } else {
        #pragma unroll
        for (int j = 0; j < 8; ++j) qv[j] = (f16)wv[j];
      }
      *reinterpret_cast<f16x8*>(&Bs[row*LDT + c8]) = qv;
    }
    __syncthreads();
    f16x8 af[MF], bf[4];
    #pragma unroll
    for (int i = 0; i < MF; ++i)
      af[i] = *reinterpret_cast<const f16x8*>(&As[(wm0 + i*16 + lr)*LDT + kg*8]);
    #pragma unroll
    for (int j = 0; j < 4; ++j)
      bf[j] = *reinterpret_cast<const f16x8*>(&Bs[(wn0 + j*16 + lr)*LDT + kg*8]);
    #pragma unroll
    for (int i = 0; i < MF; ++i)
      #pragma unroll
      for (int j = 0; j < 4; ++j)
        acc[i][j] = __builtin_amdgcn_mfma_f32_16x16x32_f16(af[i], bf[j], acc[i][j], 0, 0, 0);
    __syncthreads();
  }
  #pragma unroll
  for (int j = 0; j < 4; ++j) {
    const int col = n0 + wn0 + j*16 + lr;
    const float sv = QUANT ? scl[col] : 1.f;
    #pragma unroll
    for (int i = 0; i < MF; ++i) {
      #pragma unroll
      for (int e = 0; e < 4; ++e) {
        const int row = m0 + wm0 + i*16 + kg*4 + e;
        float y = acc[i][j][e] * sv;
        if (EPI == 1) y = 1.f / (1.f + expf(-y));
        if (EPI == 2) y += resid[(size_t)row*N + col];
        if (OUTF16) reinterpret_cast<f16*>(outp)[(size_t)row*N + col] = (f16)y;
        else        reinterpret_cast<float*>(outp)[(size_t)row*N + col] = y;
      }
    }
  }
}

// ---------------------------------------------------------------------------
extern "C" void kernel_launch(void* const* d_in, const int* in_sizes, int n_in,
                              void* d_out, int out_size, void* d_ws, size_t ws_size,
                              hipStream_t stream)
{
  (void)in_sizes; (void)n_in; (void)out_size;
  const int*   idx      = (const int*)  d_in[0];
  const float* embed    = (const float*)d_in[1];
  const float* ln_in_w  = (const float*)d_in[2];
  const float* ln1_w    = (const float*)d_in[3];
  const float* Wr       = (const float*)d_in[4];
  const float* Wk       = (const float*)d_in[5];
  const float* Wv       = (const float*)d_in[6];
  const float* Wo_t     = (const float*)d_in[7];
  const float* decay    = (const float*)d_in[8];
  const float* lnx_w    = (const float*)d_in[9];
  const float* ln2_w    = (const float*)d_in[10];
  const float* W1       = (const float*)d_in[11];
  const float* W2       = (const float*)d_in[12];
  const float* Wo_c     = (const float*)d_in[13];
  const float* ln_out_w = (const float*)d_in[14];
  float* out = (float*)d_out;

  char* p = (char*)d_ws;
  auto alloc = [&](size_t bytes) { void* q = (void*)p; p += (bytes + 255) & ~(size_t)255; return q; };
  float* h      = (float*)alloc((size_t)M*D*sizeof(float));
  f16*   xn     = (f16*)  alloc((size_t)M*D*sizeof(f16));
  float* rkv    = (float*)alloc((size_t)M*RKV*sizeof(float));   // fused r|k|v; reused as split-K partials
  float* rsb    = (float*)alloc((size_t)M*D*sizeof(float));
  f16*   abf    = (f16*)  alloc((size_t)M*FFD*sizeof(f16));
  f16*   bbf    = (f16*)  alloc((size_t)M*FFD*sizeof(f16));     // fallback only
  float* scales = (float*)alloc((size_t)NL*ROWS_PER_LAYER*sizeof(float));
  float* part   = (float*)alloc((size_t)BB*NT*D*sizeof(float));
  const size_t base_need = (size_t)(p - (char*)d_ws);
  const size_t fast_need = base_need + (NL*QL*sizeof(f16) + 256) + ((size_t)V*D*sizeof(f16) + 256);

  embed_rms_kernel<<<M, 256, 0, stream>>>(idx, embed, ln_in_w, h);

  const dim3 gS(D/256, NT, BB);   // scan1/scan3: 512 blocks
  const dim3 gS2(D/256, BB);      // scan2: 8 blocks

  if (ws_size >= fast_need) {
    // ================= FAST PATH: pre-quantized f16 weights =================
    f16* qw      = (f16*)alloc(NL*QL*sizeof(f16));
    f16* embed16 = (f16*)alloc((size_t)V*D*sizeof(f16));
    quant_kernel<<<dim3(ROWS_PER_LAYER, NL), 256, 0, stream>>>(Wr, Wk, Wv, Wo_t, W1, W2, Wo_c, qw, scales);
    cvt16_kernel<<<2048, 256, 0, stream>>>(embed, embed16, V*D/4);

    const dim3 gRKV(M/128, RKV/128);     // 16 x 24 = 384 blocks, 8 waves
    const dim3 gO(M/64, D/128);          // 32 x 8  = 256 blocks, 4 waves
    const dim3 gOC(M/64, D/128, 2);      // 32 x 8 x 2 = 512 blocks (split-K)
    const dim3 gFFN(M/128, FFD/128);     // 16 x 32 = 512 blocks, 8 waves
    const dim3 gHEAD(M/128, V/256);      // 16 x 125 = 2000 blocks, 8 waves

    for (int l = 0; l < NL; ++l) {
      const float* sl = scales + (size_t)l*ROWS_PER_LAYER;
      const f16* qb = qw + (size_t)l*QL;
      const f16 *qrkv = qb, *qo = qb + 3ull*D*D;
      const f16 *q1 = qb + 4ull*D*D, *q2 = qb + 4ull*D*D + (size_t)FFD*D;
      const f16 *qoc = qb + 4ull*D*D + 2ull*(size_t)FFD*D;
      const float* dcy = decay + (size_t)l*D;
      // ---- time mix ----
      rms_f16_kernel<<<M, 256, 0, stream>>>(h, ln1_w + (size_t)l*D, xn);
      gemm_q_kernel<128,8,3,false,true><<<gRKV, 512, 0, stream>>>(xn, qrkv, sl, nullptr, rkv, RKV, D);
      scan1_kernel<<<gS, 256, 0, stream>>>(rkv + D, rkv + 2*D, RKV, dcy, part);
      scan2_kernel<<<gS2, 256, 0, stream>>>(part);
      scan3_kernel<<<gS, 256, 0, stream>>>(rkv, rkv + D, rkv + 2*D, RKV, dcy, part, rsb);
      rms_f16_kernel<<<M, 256, 0, stream>>>(rsb, lnx_w + (size_t)l*D, xn);
      gemm_q_kernel<64,4,2,false,true><<<gO, 256, 0, stream>>>(xn, qo, sl + 3*D, h, h, D, D);
      // ---- channel mix ----
      rms_f16_kernel<<<M, 256, 0, stream>>>(h, ln2_w + (size_t)l*D, xn);
      gemm_ffn_kernel<<<gFFN, 512, 0, stream>>>(xn, q1, q2, sl + 4*D, sl + 4*D + FFD, abf, FFD, D);
      // oc: split-K x2 into rkv-buffer partials (rkv dead after scan3), then reduce
      gemm_q_kernel<64,4,0,false,true,true><<<gOC, 256, 0, stream>>>(abf, qoc, sl + 4*D + 2*FFD, nullptr, rkv, D, FFD);
      radd_kernel<<<(M*D/4)/256, 256, 0, stream>>>(h, rkv, rkv + (size_t)M*D, M*D/4);
    }
    rms_f16_kernel<<<M, 256, 0, stream>>>(h, ln_out_w, xn);
    gemm_head_kernel<<<gHEAD, 512, 0, stream>>>(xn, embed16, out, V, D);
  } else {
    // ================= FALLBACK: inline-quant path =================
    float* rbuf = rkv;                       // reuse rkv region as 3 buffers
    float* kbuf = rkv + (size_t)M*D;
    float* vbuf = rkv + 2ull*M*D;
    scales_kernel<<<dim3(ROWS_PER_LAYER, NL), 64, 0, stream>>>(Wr, Wk, Wv, Wo_t, W1, W2, Wo_c, scales);
    const dim3 gD(D/128, M/64);
    const dim3 gF(FFD/128, M/128);
    for (int l = 0; l < NL; ++l) {
      const float* sl = scales + (size_t)l*ROWS_PER_LAYER;
      const float* dcy = decay + (size_t)l*D;
      rms_f16_kernel<<<M, 256, 0, stream>>>(h, ln1_w + (size_t)l*D, xn);
      gemm_bt_kernel<64,1,true,false><<<gD, 256, 0, stream>>>(xn, Wr + (size_t)l*D*D, sl,       nullptr, rbuf, D, D);
      gemm_bt_kernel<64,0,true,false><<<gD, 256, 0, stream>>>(xn, Wk + (size_t)l*D*D, sl + D,   nullptr, kbuf, D, D);
      gemm_bt_kernel<64,0,true,false><<<gD, 256, 0, stream>>>(xn, Wv + (size_t)l*D*D, sl + 2*D, nullptr, vbuf, D, D);
      scan1_kernel<<<gS, 256, 0, stream>>>(kbuf, vbuf, D, dcy, part);
      scan2_kernel<<<gS2, 256, 0, stream>>>(part);
      scan3_kernel<<<gS, 256, 0, stream>>>(rbuf, kbuf, vbuf, D, dcy, part, rsb);
      rms_f16_kernel<<<M, 256, 0, stream>>>(rsb, lnx_w + (size_t)l*D, xn);
      gemm_bt_kernel<64,2,true,false><<<gD, 256, 0, stream>>>(xn, Wo_t + (size_t)l*D*D, sl + 3*D, h, h, D, D);
      rms_f16_kernel<<<M, 256, 0, stream>>>(h, ln2_w + (size_t)l*D, xn);
      gemm_bt_kernel<128,0,true,true><<<gF, 256, 0, stream>>>(xn, W1 + (size_t)l*FFD*D, sl + 4*D,       nullptr, abf, FFD, D);
      gemm_bt_kernel<128,0,true,true><<<gF, 256, 0, stream>>>(xn, W2 + (size_t)l*FFD*D, sl + 4*D + FFD, nullptr, bbf, FFD, D);
      silumul_kernel<<<(M*FFD/4)/256, 256, 0, stream>>>(abf, bbf, abf, M*FFD/4);
      gemm_bt_kernel<64,2,true,false><<<gD, 256, 0, stream>>>(abf, Wo_c + (size_t)l*D*FFD, sl + 4*D + 2*FFD, h, h, D, FFD);
    }
    rms_f16_kernel<<<M, 256, 0, stream>>>(h, ln_out_w, xn);
    gemm_bt_kernel<128,0,false,false><<<dim3(V/128, M/128), 256, 0, stream>>>(xn, embed, nullptr, nullptr, out, V, D);
  }
}

// Round 8
// 1514.416 us; speedup vs baseline: 1.2408x; 1.0383x over previous
//
#include <hip/hip_runtime.h>

typedef _Float16 f16;
typedef _Float16 f16x8 __attribute__((ext_vector_type(8)));
typedef _Float16 f16x4 __attribute__((ext_vector_type(4)));
typedef float f32x4 __attribute__((ext_vector_type(4)));

static constexpr int BB = 2, T = 1024, D = 1024, FFD = 4096, V = 32000, NL = 6;
static constexpr int M = BB * T;                       // 2048 rows
static constexpr int ROWS_PER_LAYER = 4*D + 2*FFD + D; // 13312 scale rows per layer
static constexpr size_t QL = 4ull*D*D + 2ull*FFD*D + (size_t)D*FFD; // 16.78M elems/layer
static constexpr int NT = 64, CT = T / NT;             // scan: 64 chunks x 16 steps
static constexpr int RKV = 3*D;                        // fused rkv row stride

// direct global->LDS, 16B per lane. lds base wave-uniform; HW writes lane i at
// lds + i*16 (m104).
__device__ __forceinline__ void gload16(const f16* g, f16* l) {
  __builtin_amdgcn_global_load_lds(
      (const __attribute__((address_space(1))) void*)g,
      (__attribute__((address_space(3))) void*)l, 16, 0, 0);
}
// counted vmcnt wait: allow N loads (the newest stage) to remain in flight.
template<int N> __device__ __forceinline__ void vm_wait() {
  static_assert(N == 2 || N == 3, "unsupported vmcnt");
  if constexpr (N == 2) asm volatile("s_waitcnt vmcnt(2)" ::: "memory");
  else                  asm volatile("s_waitcnt vmcnt(3)" ::: "memory");
}
// ring-phase boundary: all waves' reads of the oldest buffer are complete
// (consumed pre-barrier); sched_barrier pins the next stage AFTER the barrier
// so the buffer overwrite cannot be hoisted into the previous phase.
__device__ __forceinline__ void ring_barrier() {
  __builtin_amdgcn_s_barrier();
  __builtin_amdgcn_sched_barrier(0);
}

// ---------------------------------------------------------------------------
// Single-pass per-row scale + ternary-quantize to f16 (row held in registers).
// qw layout per layer: [qr(D,D) qk qv qo | q1(FFD,D) q2 | qoc(D,FFD)]
// ---------------------------------------------------------------------------
__global__ __launch_bounds__(256) void quant_kernel(
    const float* __restrict__ Wr, const float* __restrict__ Wk,
    const float* __restrict__ Wv, const float* __restrict__ Wo,
    const float* __restrict__ W1, const float* __restrict__ W2,
    const float* __restrict__ Woc, f16* __restrict__ qw, float* __restrict__ scales)
{
  const int r = blockIdx.x, l = blockIdx.y;
  const float* base; int len; size_t dst;
  if (r < 4*D) {
    const int m = r >> 10, row = r & (D-1);
    const float* Wm = (m==0) ? Wr : (m==1) ? Wk : (m==2) ? Wv : Wo;
    base = Wm + (size_t)l*D*D + (size_t)row*D; len = D;
    dst = (size_t)l*QL + (size_t)m*D*D + (size_t)row*D;
  } else if (r < 4*D + 2*FFD) {
    int row = r - 4*D;
    const int m = row >= FFD; if (m) row -= FFD;
    const float* Wm = m ? W2 : W1;
    base = Wm + (size_t)l*FFD*D + (size_t)row*D; len = D;
    dst = (size_t)l*QL + 4ull*D*D + (size_t)m*FFD*D + (size_t)row*D;
  } else {
    const int row = r - (4*D + 2*FFD);
    base = Woc + (size_t)l*D*FFD + (size_t)row*FFD; len = FFD;
    dst = (size_t)l*QL + 4ull*D*D + 2ull*FFD*D + (size_t)row*FFD;
  }
  const int nv = len >> 10;
  float4 rv[4];
  float sum = 0.f;
  #pragma unroll 4
  for (int i = 0; i < 4; ++i) {
    if (i < nv) {
      rv[i] = reinterpret_cast<const float4*>(base)[threadIdx.x + i*256];
      sum += fabsf(rv[i].x) + fabsf(rv[i].y) + fabsf(rv[i].z) + fabsf(rv[i].w);
    }
  }
  #pragma unroll
  for (int off = 32; off > 0; off >>= 1) sum += __shfl_down(sum, off);
  __shared__ float red[4]; __shared__ float sbc;
  if ((threadIdx.x & 63) == 0) red[threadIdx.x >> 6] = sum;
  __syncthreads();
  if (threadIdx.x == 0) {
    const float s = fmaxf((red[0]+red[1]+red[2]+red[3]) / (float)len, 1e-5f);
    sbc = s;
    scales[(size_t)l*ROWS_PER_LAYER + r] = s;
  }
  __syncthreads();
  const float hs = 0.5f * sbc;
  #pragma unroll 4
  for (int i = 0; i < 4; ++i) {
    if (i < nv) {
      const float4 v = rv[i];
      f16x4 q;
      q[0] = v.x > hs ? (f16)1.f : (v.x < -hs ? (f16)-1.f : (f16)0.f);
      q[1] = v.y > hs ? (f16)1.f : (v.y < -hs ? (f16)-1.f : (f16)0.f);
      q[2] = v.z > hs ? (f16)1.f : (v.z < -hs ? (f16)-1.f : (f16)0.f);
      q[3] = v.w > hs ? (f16)1.f : (v.w < -hs ? (f16)-1.f : (f16)0.f);
      reinterpret_cast<f16x4*>(qw + dst)[threadIdx.x + i*256] = q;
    }
  }
}

// f32 -> f16 bulk convert (for embed / head B operand)
__global__ __launch_bounds__(256) void cvt16_kernel(
    const float* __restrict__ x, f16* __restrict__ o, int n4)
{
  const int stride = gridDim.x * 256;
  for (int i = blockIdx.x*256 + threadIdx.x; i < n4; i += stride) {
    const float4 v = reinterpret_cast<const float4*>(x)[i];
    f16x4 q; q[0]=(f16)v.x; q[1]=(f16)v.y; q[2]=(f16)v.z; q[3]=(f16)v.w;
    reinterpret_cast<f16x4*>(o)[i] = q;
  }
}

// ---------------------------------------------------------------------------
// h = rmsnorm(embed[idx], ln_in_w), f32 out. One block (256 thr) per row.
// ---------------------------------------------------------------------------
__global__ __launch_bounds__(256) void embed_rms_kernel(
    const int* __restrict__ idx, const float* __restrict__ embed,
    const float* __restrict__ g, float* __restrict__ h)
{
  const int row = blockIdx.x;
  const int tok = idx[row];
  const float4 xv = reinterpret_cast<const float4*>(embed + (size_t)tok*D)[threadIdx.x];
  float ss = xv.x*xv.x + xv.y*xv.y + xv.z*xv.z + xv.w*xv.w;
  #pragma unroll
  for (int off = 32; off > 0; off >>= 1) ss += __shfl_down(ss, off);
  __shared__ float red[4];
  if ((threadIdx.x & 63) == 0) red[threadIdx.x >> 6] = ss;
  __syncthreads();
  const float mean = (red[0]+red[1]+red[2]+red[3]) * (1.f/(float)D);
  const float rn = rsqrtf(mean + 1e-6f);
  const float4 gv = reinterpret_cast<const float4*>(g)[threadIdx.x];
  float4 ov;
  ov.x = xv.x*rn*gv.x; ov.y = xv.y*rn*gv.y; ov.z = xv.z*rn*gv.z; ov.w = xv.w*rn*gv.w;
  reinterpret_cast<float4*>(h + (size_t)row*D)[threadIdx.x] = ov;
}

// ---------------------------------------------------------------------------
// xn = (f16) rmsnorm(x, g). One block (256 thr) per row of 1024.
// ---------------------------------------------------------------------------
__global__ __launch_bounds__(256) void rms_f16_kernel(
    const float* __restrict__ x, const float* __restrict__ g, f16* __restrict__ o)
{
  const int row = blockIdx.x;
  const float4 xv = reinterpret_cast<const float4*>(x + (size_t)row*D)[threadIdx.x];
  float ss = xv.x*xv.x + xv.y*xv.y + xv.z*xv.z + xv.w*xv.w;
  #pragma unroll
  for (int off = 32; off > 0; off >>= 1) ss += __shfl_down(ss, off);
  __shared__ float red[4];
  if ((threadIdx.x & 63) == 0) red[threadIdx.x >> 6] = ss;
  __syncthreads();
  const float mean = (red[0]+red[1]+red[2]+red[3]) * (1.f/(float)D);
  const float rn = rsqrtf(mean + 1e-6f);
  const float4 gv = reinterpret_cast<const float4*>(g)[threadIdx.x];
  f16x4 ov;
  ov[0] = (f16)(xv.x*rn*gv.x); ov[1] = (f16)(xv.y*rn*gv.y);
  ov[2] = (f16)(xv.z*rn*gv.z); ov[3] = (f16)(xv.w*rn*gv.w);
  reinterpret_cast<f16x4*>(o + (size_t)row*D)[threadIdx.x] = ov;
}

// ---------------------------------------------------------------------------
// Fused: w = h + (p0 + p1); h = w; xn = (f16) rmsnorm(w, g).
// Replaces radd + rms (saves one launch + one 8MB pass per layer).
// ---------------------------------------------------------------------------
__global__ __launch_bounds__(256) void rms_radd_kernel(
    float* __restrict__ h, const float* __restrict__ p0,
    const float* __restrict__ p1, const float* __restrict__ g,
    f16* __restrict__ o)
{
  const int row = blockIdx.x;
  const size_t off = (size_t)row*D/4 + threadIdx.x;
  float4 hv = reinterpret_cast<const float4*>(h)[off];
  const float4 a = reinterpret_cast<const float4*>(p0)[off];
  const float4 b = reinterpret_cast<const float4*>(p1)[off];
  hv.x += a.x + b.x; hv.y += a.y + b.y; hv.z += a.z + b.z; hv.w += a.w + b.w;
  reinterpret_cast<float4*>(h)[off] = hv;
  float ss = hv.x*hv.x + hv.y*hv.y + hv.z*hv.z + hv.w*hv.w;
  #pragma unroll
  for (int o2 = 32; o2 > 0; o2 >>= 1) ss += __shfl_down(ss, o2);
  __shared__ float red[4];
  if ((threadIdx.x & 63) == 0) red[threadIdx.x >> 6] = ss;
  __syncthreads();
  const float mean = (red[0]+red[1]+red[2]+red[3]) * (1.f/(float)D);
  const float rn = rsqrtf(mean + 1e-6f);
  const float4 gv = reinterpret_cast<const float4*>(g)[threadIdx.x];
  f16x4 ov;
  ov[0] = (f16)(hv.x*rn*gv.x); ov[1] = (f16)(hv.y*rn*gv.y);
  ov[2] = (f16)(hv.z*rn*gv.z); ov[3] = (f16)(hv.w*rn*gv.w);
  reinterpret_cast<f16x4*>(o + (size_t)row*D)[threadIdx.x] = ov;
}

// ---------------------------------------------------------------------------
// Time-mix recurrence: chunked prefix sum over T.
// scan1: per-chunk partial sums. scan23: redundant per-block exclusive prefix
// (L2-hot, same ascending-j order as the old scan2) + chunk walk + output.
// ---------------------------------------------------------------------------
__global__ __launch_bounds__(256) void scan1_kernel(
    const float* __restrict__ k, const float* __restrict__ v, int ld,
    const float* __restrict__ decay, float* __restrict__ part)
{
  const int d = blockIdx.x*256 + threadIdx.x;
  const int c = blockIdx.y, b = blockIdx.z;
  const float dec = 1.f / (1.f + expf(-decay[d]));
  const float ldc = logf(fmaxf(dec, 1e-7f));
  float sum = 0.f;
  const int row0 = b*T + c*CT;
  #pragma unroll 4
  for (int t = 0; t < CT; ++t) {
    const size_t i = (size_t)(row0 + t)*ld + d;
    const float scale = expf((float)(c*CT + t) * ldc);
    sum += (k[i] * v[i]) / fmaxf(scale, 1e-10f);
  }
  part[((size_t)b*NT + c)*D + d] = sum;
}

__global__ __launch_bounds__(256) void scan23_kernel(
    const float* __restrict__ r, const float* __restrict__ k,
    const float* __restrict__ v, int ld, const float* __restrict__ decay,
    const float* __restrict__ part, float* __restrict__ rs)
{
  const int d = blockIdx.x*256 + threadIdx.x;
  const int c = blockIdx.y, b = blockIdx.z;
  const float dec = 1.f / (1.f + expf(-decay[d]));
  const float ldc = logf(fmaxf(dec, 1e-7f));
  float cum = 0.f;
  for (int j = 0; j < c; ++j) cum += part[((size_t)b*NT + j)*D + d];
  const int row0 = b*T + c*CT;
  #pragma unroll 4
  for (int t = 0; t < CT; ++t) {
    const size_t i = (size_t)(row0 + t)*ld + d;
    const float scale = expf((float)(c*CT + t) * ldc);
    cum += (k[i] * v[i]) / fmaxf(scale, 1e-10f);
    rs[(size_t)(row0 + t)*D + d] = r[i] * (cum * scale);
  }
}

// fallback-path kernels -------------------------------------------------------
__global__ __launch_bounds__(256) void scan2_kernel(float* __restrict__ part)
{
  const int d = blockIdx.x*256 + threadIdx.x;
  const int b = blockIdx.y;
  float run = 0.f;
  #pragma unroll 8
  for (int c = 0; c < NT; ++c) {
    const size_t i = ((size_t)b*NT + c)*D + d;
    const float t = part[i];
    part[i] = run;
    run += t;
  }
}

__global__ __launch_bounds__(256) void scan3_kernel(
    const float* __restrict__ r, const float* __restrict__ k,
    const float* __restrict__ v, int ld, const float* __restrict__ decay,
    const float* __restrict__ part, float* __restrict__ rs)
{
  const int d = blockIdx.x*256 + threadIdx.x;
  const int c = blockIdx.y, b = blockIdx.z;
  const float dec = 1.f / (1.f + expf(-decay[d]));
  const float ldc = logf(fmaxf(dec, 1e-7f));
  float cum = part[((size_t)b*NT + c)*D + d];
  const int row0 = b*T + c*CT;
  #pragma unroll 4
  for (int t = 0; t < CT; ++t) {
    const size_t i = (size_t)(row0 + t)*ld + d;
    const float scale = expf((float)(c*CT + t) * ldc);
    cum += (k[i] * v[i]) / fmaxf(scale, 1e-10f);
    rs[(size_t)(row0 + t)*D + d] = r[i] * (cum * scale);
  }
}

__global__ __launch_bounds__(256) void silumul_kernel(
    const f16* __restrict__ a, const f16* __restrict__ b, f16* __restrict__ o, int n4)
{
  const int i = blockIdx.x*256 + threadIdx.x;
  if (i >= n4) return;
  const f16x4 av = reinterpret_cast<const f16x4*>(a)[i];
  const f16x4 bv = reinterpret_cast<const f16x4*>(b)[i];
  f16x4 ov;
  #pragma unroll
  for (int j = 0; j < 4; ++j) {
    const float x = (float)av[j];
    ov[j] = (f16)((x / (1.f + expf(-x))) * (float)bv[j]);
  }
  reinterpret_cast<f16x4*>(o)[i] = ov;
}

// ---------------------------------------------------------------------------
// XCD-chunked bijective block swizzle (m204): contiguous logical ids per XCD.
// ---------------------------------------------------------------------------
__device__ __forceinline__ int xcd_swizzle(int fid, int nwg) {
  const int q = nwg >> 3, r = nwg & 7, x = fid & 7, o = fid >> 3;
  return (x < r ? x*(q+1) : r*(q+1) + (x-r)*q) + o;
}

// ---------------------------------------------------------------------------
// RING GEMM (3-buffer, depth-2 prefetch, counted vmcnt, ONE barrier/K-step):
// out[M,N] = epi(scl[n] * A[M,K] @ Bq[N,K]^T). BK=32, linear LDS.
// Loop: vmcnt(CALLS) -> s_barrier -> sched_barrier -> stage(t+2) ->
//       ds_read buf(t%3) -> MFMA. Loads from stage t+1 stay in flight across
//       the barrier (never drained to 0). EPI: 0 none, 2 +resid, 3 sigmoid
//       iff col<D. SPLITK: gridDim.z pieces write outp + z*M*N.
// ---------------------------------------------------------------------------
template<int BM, int NW, int EPI, bool OUTF16, bool SCALE, bool SPLITK = false>
__global__ __launch_bounds__(NW*64) void gemm_q_kernel(
    const f16* __restrict__ A, const f16* __restrict__ Bq,
    const float* __restrict__ scl, const float* __restrict__ resid,
    void* __restrict__ outp, int N, int K)
{
  constexpr int WN = 2;                  // waves along N (BN=128)
  constexpr int WM = NW / WN;
  constexpr int MF = BM / (WM*16);
  constexpr int ACALLS = BM / (16*NW);
  constexpr int BCALLS = 128 / (16*NW);
  constexpr int VCNT = ACALLS + BCALLS;
  __shared__ f16 As[3][BM*32];
  __shared__ f16 Bs[3][128*32];

  const int tid = threadIdx.x;
  const int wave = tid >> 6, lane = tid & 63;
  const int gx = gridDim.x, nwg = gx * gridDim.y;
  const int wg = xcd_swizzle(blockIdx.x + blockIdx.y*gx, nwg);
  const int m0 = (wg % gx) * BM, n0 = (wg / gx) * 128;
  const int lr = lane & 15, kg = lane >> 4;
  const int wm0 = (wave / WN) * (MF*16), wn0 = (wave % WN) * 64;
  const int grow = lane >> 2;
  const int gcol = (lane & 3) * 8;
  const f16* Ab = A  + (size_t)(m0 + grow)*K + gcol;
  const f16* Bb = Bq + (size_t)(n0 + grow)*K + gcol;

  int kbeg = 0, kend = K;
  size_t obase = 0;
  if (SPLITK) {
    const int kc = K / gridDim.z;
    kbeg = blockIdx.z * kc; kend = kbeg + kc;
    obase = (size_t)blockIdx.z * M * (size_t)N;
  }
  const int NKT = (kend - kbeg) / 32;

  auto stage = [&](int buf, int k0) {
    #pragma unroll
    for (int c = 0; c < ACALLS; ++c) {
      const int rb = (c*NW + wave) * 16;
      gload16(Ab + (size_t)rb*K + k0, &As[buf][rb*32]);
    }
    #pragma unroll
    for (int c = 0; c < BCALLS; ++c) {
      const int rb = (c*NW + wave) * 16;
      gload16(Bb + (size_t)rb*K + k0, &Bs[buf][rb*32]);
    }
  };

  f32x4 acc[MF][4] = {};
  stage(0, kbeg);
  stage(1, kbeg + 32);

  int cur = 0;
  for (int t = 0; t < NKT; ++t) {
    vm_wait<VCNT>();          // stage t landed; stage t+1 may remain in flight
    ring_barrier();           // all waves done reading buf (t-1)%3
    if (t + 2 < NKT) {
      int nb = cur + 2; if (nb >= 3) nb -= 3;
      stage(nb, kbeg + (t + 2) * 32);
    }
    f16x8 af[MF], bf[4];
    #pragma unroll
    for (int i = 0; i < MF; ++i)
      af[i] = *reinterpret_cast<const f16x8*>(&As[cur][(wm0 + i*16 + lr)*32 + kg*8]);
    #pragma unroll
    for (int j = 0; j < 4; ++j)
      bf[j] = *reinterpret_cast<const f16x8*>(&Bs[cur][(wn0 + j*16 + lr)*32 + kg*8]);
    #pragma unroll
    for (int i = 0; i < MF; ++i)
      #pragma unroll
      for (int j = 0; j < 4; ++j)
        acc[i][j] = __builtin_amdgcn_mfma_f32_16x16x32_f16(af[i], bf[j], acc[i][j], 0, 0, 0);
    ++cur; if (cur == 3) cur = 0;
  }

  // C/D frag layout: col=lane&15, row=(lane>>4)*4+e
  #pragma unroll
  for (int j = 0; j < 4; ++j) {
    const int col = n0 + wn0 + j*16 + lr;
    const float sv = SCALE ? scl[col] : 1.f;
    #pragma unroll
    for (int i = 0; i < MF; ++i) {
      #pragma unroll
      for (int e = 0; e < 4; ++e) {
        const int row = m0 + wm0 + i*16 + kg*4 + e;
        float y = acc[i][j][e] * sv;
        if (EPI == 3 && col < D) y = 1.f / (1.f + expf(-y));
        if (EPI == 2) y += resid[(size_t)row*N + col];
        if (OUTF16) reinterpret_cast<f16*>(outp)[(size_t)row*N + col] = (f16)y;
        else        reinterpret_cast<float*>(outp)[obase + (size_t)row*N + col] = y;
      }
    }
  }
}

// ---------------------------------------------------------------------------
// RING HEAD GEMM: 128x256 tile, 8 waves, same 3-buffer counted-vmcnt ring.
// ---------------------------------------------------------------------------
__global__ __launch_bounds__(512) void gemm_head_kernel(
    const f16* __restrict__ A, const f16* __restrict__ Bq,
    float* __restrict__ out, int N, int K)
{
  constexpr int BM = 128, BN = 256;
  __shared__ f16 As[3][BM*32];
  __shared__ f16 Bs[3][BN*32];
  const int tid = threadIdx.x;
  const int wave = tid >> 6, lane = tid & 63;
  const int gx = gridDim.x, nwg = gx * gridDim.y;
  const int wg = xcd_swizzle(blockIdx.x + blockIdx.y*gx, nwg);
  const int m0 = (wg % gx) * BM, n0 = (wg / gx) * BN;
  const int lr = lane & 15, kg = lane >> 4;
  const int wm0 = (wave >> 2) * 64, wn0 = (wave & 3) * 64;
  const int grow = lane >> 2, gcol = (lane & 3) * 8;
  const f16* Ab = A  + (size_t)(m0 + grow)*K + gcol;
  const f16* Bb = Bq + (size_t)(n0 + grow)*K + gcol;

  auto stage = [&](int buf, int k0) {
    gload16(Ab + (size_t)(wave*16)*K + k0, &As[buf][(wave*16)*32]);
    gload16(Bb + (size_t)(wave*16)*K + k0, &Bs[buf][(wave*16)*32]);
    gload16(Bb + (size_t)((wave+8)*16)*K + k0, &Bs[buf][((wave+8)*16)*32]);
  };

  f32x4 acc[4][4] = {};
  stage(0, 0);
  stage(1, 32);

  const int NKT = K / 32;
  int cur = 0;
  for (int t = 0; t < NKT; ++t) {
    vm_wait<3>();
    ring_barrier();
    if (t + 2 < NKT) {
      int nb = cur + 2; if (nb >= 3) nb -= 3;
      stage(nb, (t + 2) * 32);
    }
    f16x8 af[4], bf[4];
    #pragma unroll
    for (int i = 0; i < 4; ++i)
      af[i] = *reinterpret_cast<const f16x8*>(&As[cur][(wm0 + i*16 + lr)*32 + kg*8]);
    #pragma unroll
    for (int j = 0; j < 4; ++j)
      bf[j] = *reinterpret_cast<const f16x8*>(&Bs[cur][(wn0 + j*16 + lr)*32 + kg*8]);
    #pragma unroll
    for (int i = 0; i < 4; ++i)
      #pragma unroll
      for (int j = 0; j < 4; ++j)
        acc[i][j] = __builtin_amdgcn_mfma_f32_16x16x32_f16(af[i], bf[j], acc[i][j], 0, 0, 0);
    ++cur; if (cur == 3) cur = 0;
  }
  #pragma unroll
  for (int j = 0; j < 4; ++j) {
    const int col = n0 + wn0 + j*16 + lr;
    #pragma unroll
    for (int i = 0; i < 4; ++i) {
      #pragma unroll
      for (int e = 0; e < 4; ++e) {
        const int row = m0 + wm0 + i*16 + kg*4 + e;
        out[(size_t)row*N + col] = acc[i][j][e];
      }
    }
  }
}

// ---------------------------------------------------------------------------
// RING FUSED FFN GEMM: g = (f16)( silu(s1[n]*A@B1^T) * (s2[n]*A@B2^T) ).
// 128x128 tile, 8 waves, 3-buffer ring (3 operands staged per K-step).
// ---------------------------------------------------------------------------
__global__ __launch_bounds__(512) void gemm_ffn_kernel(
    const f16* __restrict__ A, const f16* __restrict__ B1, const f16* __restrict__ B2,
    const float* __restrict__ s1, const float* __restrict__ s2,
    f16* __restrict__ outg, int N, int K)
{
  constexpr int BM = 128, BN = 128;
  __shared__ f16 As [3][BM*32];
  __shared__ f16 B1s[3][BN*32];
  __shared__ f16 B2s[3][BN*32];
  const int tid = threadIdx.x;
  const int wave = tid >> 6, lane = tid & 63;
  const int gx = gridDim.x, nwg = gx * gridDim.y;
  const int wg = xcd_swizzle(blockIdx.x + blockIdx.y*gx, nwg);
  const int m0 = (wg % gx) * BM, n0 = (wg / gx) * BN;
  const int lr = lane & 15, kg = lane >> 4;
  const int wm0 = (wave >> 1) * 32, wn0 = (wave & 1) * 64;  // 8 waves: 4M x 2N
  const int grow = lane >> 2, gcol = (lane & 3) * 8;
  const f16* Ab  = A  + (size_t)(m0 + grow)*K + gcol;
  const f16* B1b = B1 + (size_t)(n0 + grow)*K + gcol;
  const f16* B2b = B2 + (size_t)(n0 + grow)*K + gcol;

  auto stage = [&](int buf, int k0) {
    const int rb = wave * 16;
    gload16(Ab  + (size_t)rb*K + k0, &As [buf][rb*32]);
    gload16(B1b + (size_t)rb*K + k0, &B1s[buf][rb*32]);
    gload16(B2b + (size_t)rb*K + k0, &B2s[buf][rb*32]);
  };

  f32x4 aca[2][4] = {};
  f32x4 acb[2][4] = {};
  stage(0, 0);
  stage(1, 32);

  const int NKT = K / 32;
  int cur = 0;
  for (int t = 0; t < NKT; ++t) {
    vm_wait<3>();
    ring_barrier();
    if (t + 2 < NKT) {
      int nb = cur + 2; if (nb >= 3) nb -= 3;
      stage(nb, (t + 2) * 32);
    }
    f16x8 af[2], b1f[4], b2f[4];
    #pragma unroll
    for (int i = 0; i < 2; ++i)
      af[i] = *reinterpret_cast<const f16x8*>(&As[cur][(wm0 + i*16 + lr)*32 + kg*8]);
    #pragma unroll
    for (int j = 0; j < 4; ++j) {
      b1f[j] = *reinterpret_cast<const f16x8*>(&B1s[cur][(wn0 + j*16 + lr)*32 + kg*8]);
      b2f[j] = *reinterpret_cast<const f16x8*>(&B2s[cur][(wn0 + j*16 + lr)*32 + kg*8]);
    }
    #pragma unroll
    for (int i = 0; i < 2; ++i)
      #pragma unroll
      for (int j = 0; j < 4; ++j) {
        aca[i][j] = __builtin_amdgcn_mfma_f32_16x16x32_f16(af[i], b1f[j], aca[i][j], 0, 0, 0);
        acb[i][j] = __builtin_amdgcn_mfma_f32_16x16x32_f16(af[i], b2f[j], acb[i][j], 0, 0, 0);
      }
    ++cur; if (cur == 3) cur = 0;
  }
  #pragma unroll
  for (int j = 0; j < 4; ++j) {
    const int col = n0 + wn0 + j*16 + lr;
    const float sa = s1[col], sb = s2[col];
    #pragma unroll
    for (int i = 0; i < 2; ++i) {
      #pragma unroll
      for (int e = 0; e < 4; ++e) {
        const int row = m0 + wm0 + i*16 + kg*4 + e;
        const float a = aca[i][j][e] * sa;
        const float b = acb[i][j][e] * sb;
        outg[(size_t)row*N + col] = (f16)((a / (1.f + expf(-a))) * b);
      }
    }
  }
}

// ---------------------------------------------------------------------------
// FALLBACK GEMM: inline quantize from f32 weights (used if ws too small).
// ---------------------------------------------------------------------------
__global__ __launch_bounds__(64) void scales_kernel(
    const float* __restrict__ Wr, const float* __restrict__ Wk,
    const float* __restrict__ Wv, const float* __restrict__ Wo,
    const float* __restrict__ W1, const float* __restrict__ W2,
    const float* __restrict__ Woc, float* __restrict__ s)
{
  const int r = blockIdx.x, l = blockIdx.y;
  const float* base; int len;
  if (r < 4*D) {
    const int m = r >> 10, row = r & (D-1);
    const float* Wm = (m==0) ? Wr : (m==1) ? Wk : (m==2) ? Wv : Wo;
    base = Wm + (size_t)l*D*D + (size_t)row*D; len = D;
  } else if (r < 4*D + 2*FFD) {
    int row = r - 4*D;
    const float* Wm = (row < FFD) ? W1 : W2;
    if (row >= FFD) row -= FFD;
    base = Wm + (size_t)l*FFD*D + (size_t)row*D; len = D;
  } else {
    const int row = r - (4*D + 2*FFD);
    base = Woc + (size_t)l*D*FFD + (size_t)row*FFD; len = FFD;
  }
  float sum = 0.f;
  for (int i = threadIdx.x; i < len; i += 64) sum += fabsf(base[i]);
  #pragma unroll
  for (int off = 32; off > 0; off >>= 1) sum += __shfl_down(sum, off);
  if (threadIdx.x == 0)
    s[(size_t)l*ROWS_PER_LAYER + r] = fmaxf(sum / (float)len, 1e-5f);
}

template<int BM, int EPI, bool QUANT, bool OUTF16>
__global__ __launch_bounds__(256) void gemm_bt_kernel(
    const f16* __restrict__ A, const float* __restrict__ Bw,
    const float* __restrict__ scl, const float* __restrict__ resid,
    void* __restrict__ outp, int N, int K)
{
  constexpr int BN = 128, LDT = 40;
  constexpr int MF = (BM == 128) ? 4 : 2;
  __shared__ f16 As[BM*LDT];
  __shared__ f16 Bs[BN*LDT];
  const int tid = threadIdx.x;
  const int m0 = blockIdx.y * BM, n0 = blockIdx.x * BN;
  const int wave = tid >> 6, lane = tid & 63;
  const int lr = lane & 15, kg = lane >> 4;
  const int wm0 = (wave >> 1) * (MF*16), wn0 = (wave & 1) * 64;
  f32x4 acc[MF][4] = {};
  for (int k0 = 0; k0 < K; k0 += 32) {
    #pragma unroll
    for (int c = 0; c < (BM*4)/256; ++c) {
      const int chunk = tid + c*256;
      const int row = chunk >> 2, c8 = (chunk & 3) << 3;
      *reinterpret_cast<f16x8*>(&As[row*LDT + c8]) =
        *reinterpret_cast<const f16x8*>(A + (size_t)(m0+row)*K + k0 + c8);
    }
    #pragma unroll
    for (int c = 0; c < 2; ++c) {
      const int chunk = tid + c*256;
      const int row = chunk >> 2, c8 = (chunk & 3) << 3;
      const float* bp = Bw + (size_t)(n0+row)*K + k0 + c8;
      const float4 f0 = *reinterpret_cast<const float4*>(bp);
      const float4 f1 = *reinterpret_cast<const float4*>(bp + 4);
      const float wv[8] = {f0.x,f0.y,f0.z,f0.w,f1.x,f1.y,f1.z,f1.w};
      f16x8 qv;
      if (QUANT) {
        const float hs = 0.5f * scl[n0+row];
        #pragma unroll
        for (int j = 0; j < 8; ++j)
          qv[j] = wv[j] > hs ? (f16)1.f : (wv[j] < -hs ? (f16)(-1.f) : (f16)0.f);
      } else {
        #pragma unroll
        for (int j = 0; j < 8; ++j) qv[j] = (f16)wv[j];
      }
      *reinterpret_cast<f16x8*>(&Bs[row*LDT + c8]) = qv;
    }
    __syncthreads();
    f16x8 af[MF], bf[4];
    #pragma unroll
    for (int i = 0; i < MF; ++i)
      af[i] = *reinterpret_cast<const f16x8*>(&As[(wm0 + i*16 + lr)*LDT + kg*8]);
    #pragma unroll
    for (int j = 0; j < 4; ++j)
      bf[j] = *reinterpret_cast<const f16x8*>(&Bs[(wn0 + j*16 + lr)*LDT + kg*8]);
    #pragma unroll
    for (int i = 0; i < MF; ++i)
      #pragma unroll
      for (int j = 0; j < 4; ++j)
        acc[i][j] = __builtin_amdgcn_mfma_f32_16x16x32_f16(af[i], bf[j], acc[i][j], 0, 0, 0);
    __syncthreads();
  }
  #pragma unroll
  for (int j = 0; j < 4; ++j) {
    const int col = n0 + wn0 + j*16 + lr;
    const float sv = QUANT ? scl[col] : 1.f;
    #pragma unroll
    for (int i = 0; i < MF; ++i) {
      #pragma unroll
      for (int e = 0; e < 4; ++e) {
        const int row = m0 + wm0 + i*16 + kg*4 + e;
        float y = acc[i][j][e] * sv;
        if (EPI == 1) y = 1.f / (1.f + expf(-y));
        if (EPI == 2) y += resid[(size_t)row*N + col];
        if (OUTF16) reinterpret_cast<f16*>(outp)[(size_t)row*N + col] = (f16)y;
        else        reinterpret_cast<float*>(outp)[(size_t)row*N + col] = y;
      }
    }
  }
}

// ---------------------------------------------------------------------------
extern "C" void kernel_launch(void* const* d_in, const int* in_sizes, int n_in,
                              void* d_out, int out_size, void* d_ws, size_t ws_size,
                              hipStream_t stream)
{
  (void)in_sizes; (void)n_in; (void)out_size;
  const int*   idx      = (const int*)  d_in[0];
  const float* embed    = (const float*)d_in[1];
  const float* ln_in_w  = (const float*)d_in[2];
  const float* ln1_w    = (const float*)d_in[3];
  const float* Wr       = (const float*)d_in[4];
  const float* Wk       = (const float*)d_in[5];
  const float* Wv       = (const float*)d_in[6];
  const float* Wo_t     = (const float*)d_in[7];
  const float* decay    = (const float*)d_in[8];
  const float* lnx_w    = (const float*)d_in[9];
  const float* ln2_w    = (const float*)d_in[10];
  const float* W1       = (const float*)d_in[11];
  const float* W2       = (const float*)d_in[12];
  const float* Wo_c     = (const float*)d_in[13];
  const float* ln_out_w = (const float*)d_in[14];
  float* out = (float*)d_out;

  char* p = (char*)d_ws;
  auto alloc = [&](size_t bytes) { void* q = (void*)p; p += (bytes + 255) & ~(size_t)255; return q; };
  float* h      = (float*)alloc((size_t)M*D*sizeof(float));
  f16*   xn     = (f16*)  alloc((size_t)M*D*sizeof(f16));
  float* rkv    = (float*)alloc((size_t)M*RKV*sizeof(float));   // fused r|k|v; reused as split-K partials
  float* rsb    = (float*)alloc((size_t)M*D*sizeof(float));
  f16*   abf    = (f16*)  alloc((size_t)M*FFD*sizeof(f16));
  f16*   bbf    = (f16*)  alloc((size_t)M*FFD*sizeof(f16));     // fallback only
  float* scales = (float*)alloc((size_t)NL*ROWS_PER_LAYER*sizeof(float));
  float* part   = (float*)alloc((size_t)BB*NT*D*sizeof(float));
  const size_t base_need = (size_t)(p - (char*)d_ws);
  const size_t fast_need = base_need + (NL*QL*sizeof(f16) + 256) + ((size_t)V*D*sizeof(f16) + 256);

  embed_rms_kernel<<<M, 256, 0, stream>>>(idx, embed, ln_in_w, h);

  const dim3 gS(D/256, NT, BB);   // scan1/scan23: 512 blocks
  const dim3 gS2(D/256, BB);      // scan2 (fallback): 8 blocks

  if (ws_size >= fast_need) {
    // ================= FAST PATH: pre-quantized f16 weights =================
    f16* qw      = (f16*)alloc(NL*QL*sizeof(f16));
    f16* embed16 = (f16*)alloc((size_t)V*D*sizeof(f16));
    quant_kernel<<<dim3(ROWS_PER_LAYER, NL), 256, 0, stream>>>(Wr, Wk, Wv, Wo_t, W1, W2, Wo_c, qw, scales);
    cvt16_kernel<<<2048, 256, 0, stream>>>(embed, embed16, V*D/4);

    const dim3 gRKV(M/128, RKV/128);     // 16 x 24 = 384 blocks, 8 waves
    const dim3 gO(M/64, D/128);          // 32 x 8  = 256 blocks, 4 waves
    const dim3 gOC(M/64, D/128, 2);      // 512 blocks (split-K x2)
    const dim3 gFFN(M/128, FFD/128);     // 16 x 32 = 512 blocks, 8 waves
    const dim3 gHEAD(M/128, V/256);      // 16 x 125 = 2000 blocks, 8 waves

    rms_f16_kernel<<<M, 256, 0, stream>>>(h, ln1_w, xn);   // first layer's ln1
    for (int l = 0; l < NL; ++l) {
      const float* sl = scales + (size_t)l*ROWS_PER_LAYER;
      const f16* qb = qw + (size_t)l*QL;
      const f16 *qrkv = qb, *qo = qb + 3ull*D*D;
      const f16 *q1 = qb + 4ull*D*D, *q2 = qb + 4ull*D*D + (size_t)FFD*D;
      const f16 *qoc = qb + 4ull*D*D + 2ull*(size_t)FFD*D;
      const float* dcy = decay + (size_t)l*D;
      // ---- time mix ----
      gemm_q_kernel<128,8,3,false,true><<<gRKV, 512, 0, stream>>>(xn, qrkv, sl, nullptr, rkv, RKV, D);
      scan1_kernel<<<gS, 256, 0, stream>>>(rkv + D, rkv + 2*D, RKV, dcy, part);
      scan23_kernel<<<gS, 256, 0, stream>>>(rkv, rkv + D, rkv + 2*D, RKV, dcy, part, rsb);
      rms_f16_kernel<<<M, 256, 0, stream>>>(rsb, lnx_w + (size_t)l*D, xn);
      gemm_q_kernel<64,4,2,false,true><<<gO, 256, 0, stream>>>(xn, qo, sl + 3*D, h, h, D, D);
      // ---- channel mix ----
      rms_f16_kernel<<<M, 256, 0, stream>>>(h, ln2_w + (size_t)l*D, xn);
      gemm_ffn_kernel<<<gFFN, 512, 0, stream>>>(xn, q1, q2, sl + 4*D, sl + 4*D + FFD, abf, FFD, D);
      gemm_q_kernel<64,4,0,false,true,true><<<gOC, 256, 0, stream>>>(abf, qoc, sl + 4*D + 2*FFD, nullptr, rkv, D, FFD);
      // fused: h += p0+p1, xn = rms(h, next norm weight)
      const float* gnext = (l + 1 < NL) ? (ln1_w + (size_t)(l+1)*D) : ln_out_w;
      rms_radd_kernel<<<M, 256, 0, stream>>>(h, rkv, rkv + (size_t)M*D, gnext, xn);
    }
    gemm_head_kernel<<<gHEAD, 512, 0, stream>>>(xn, embed16, out, V, D);
  } else {
    // ================= FALLBACK: inline-quant path =================
    float* rbuf = rkv;
    float* kbuf = rkv + (size_t)M*D;
    float* vbuf = rkv + 2ull*M*D;
    scales_kernel<<<dim3(ROWS_PER_LAYER, NL), 64, 0, stream>>>(Wr, Wk, Wv, Wo_t, W1, W2, Wo_c, scales);
    const dim3 gD(D/128, M/64);
    const dim3 gF(FFD/128, M/128);
    for (int l = 0; l < NL; ++l) {
      const float* sl = scales + (size_t)l*ROWS_PER_LAYER;
      const float* dcy = decay + (size_t)l*D;
      rms_f16_kernel<<<M, 256, 0, stream>>>(h, ln1_w + (size_t)l*D, xn);
      gemm_bt_kernel<64,1,true,false><<<gD, 256, 0, stream>>>(xn, Wr + (size_t)l*D*D, sl,       nullptr, rbuf, D, D);
      gemm_bt_kernel<64,0,true,false><<<gD, 256, 0, stream>>>(xn, Wk + (size_t)l*D*D, sl + D,   nullptr, kbuf, D, D);
      gemm_bt_kernel<64,0,true,false><<<gD, 256, 0, stream>>>(xn, Wv + (size_t)l*D*D, sl + 2*D, nullptr, vbuf, D, D);
      scan1_kernel<<<gS, 256, 0, stream>>>(kbuf, vbuf, D, dcy, part);
      scan2_kernel<<<gS2, 256, 0, stream>>>(part);
      scan3_kernel<<<gS, 256, 0, stream>>>(rbuf, kbuf, vbuf, D, dcy, part, rsb);
      rms_f16_kernel<<<M, 256, 0, stream>>>(rsb, lnx_w + (size_t)l*D, xn);
      gemm_bt_kernel<64,2,true,false><<<gD, 256, 0, stream>>>(xn, Wo_t + (size_t)l*D*D, sl + 3*D, h, h, D, D);
      rms_f16_kernel<<<M, 256, 0, stream>>>(h, ln2_w + (size_t)l*D, xn);
      gemm_bt_kernel<128,0,true,true><<<gF, 256, 0, stream>>>(xn, W1 + (size_t)l*FFD*D, sl + 4*D,       nullptr, abf, FFD, D);
      gemm_bt_kernel<128,0,true,true><<<gF, 256, 0, stream>>>(xn, W2 + (size_t)l*FFD*D, sl + 4*D + FFD, nullptr, bbf, FFD, D);
      silumul_kernel<<<(M*FFD/4)/256, 256, 0, stream>>>(abf, bbf, abf, M*FFD/4);
      gemm_bt_kernel<64,2,true,false><<<gD, 256, 0, stream>>>(abf, Wo_c + (size_t)l*D*FFD, sl + 4*D + 2*FFD, h, h, D, FFD);
    }
    rms_f16_kernel<<<M, 256, 0, stream>>>(h, ln_out_w, xn);
    gemm_bt_kernel<128,0,false,false><<<dim3(V/128, M/128), 256, 0, stream>>>(xn, embed, nullptr, nullptr, out, V, D);
  }
}